// Round 1
// baseline (2239.931 us; speedup 1.0000x reference)
//
#include <hip/hip_runtime.h>
#include <math.h>

#define HW 16384   // 128*128

// ---------------------------------------------------------------------------
// Weight transposes (run every launch; cheap).
//  wTd  [k][c][oc]       = w_dcn[oc][c][k]
//  wT1  [c*9+t][oc]      = w1[oc][c][t]
//  wT2  [c*9+t][oc]      = w2[oc][c][t]
//  wTom [ci*9+t][oc(27)] = w_om[oc][ci][t]
// ---------------------------------------------------------------------------
__global__ __launch_bounds__(256) void transpose_weights(
    const float* __restrict__ w_dcn, const float* __restrict__ w1,
    const float* __restrict__ w2, const float* __restrict__ w_om,
    float* __restrict__ wTd, float* __restrict__ wT1,
    float* __restrict__ wT2, float* __restrict__ wTom)
{
    int i = blockIdx.x * 256 + threadIdx.x;
    if (i < 128 * 128 * 9) {
        int t = i % 9;
        int c = (i / 9) & 127;
        int oc = i / (9 * 128);
        wTd[(t * 128 + c) * 128 + oc] = w_dcn[i];
        wT1[(c * 9 + t) * 128 + oc] = w1[i];
        wT2[(c * 9 + t) * 128 + oc] = w2[i];
    }
    if (i < 27 * 129 * 9) {
        int t = i % 9;
        int c = (i / 9) % 129;
        int oc = i / (9 * 129);
        wTom[(c * 9 + t) * 27 + oc] = w_om[i];
    }
}

// ---------------------------------------------------------------------------
// Kernel A: om = conv3x3(concat(x, clip(U)), w_om) + b_om, with
//   channels 18..26 transformed to 2*sigmoid(.) (the DCN mask).
// Block: 256 threads = 64 pixels (16x4 tile) x 4 groups of 7 output chans.
// ---------------------------------------------------------------------------
__global__ __launch_bounds__(256) void k_om(
    const float* __restrict__ x, const float* __restrict__ U,
    const float* __restrict__ wTom, const float* __restrict__ b_om,
    float* __restrict__ om)
{
    const int tx = blockIdx.x;          // 0..7  (16 wide)
    const int ty = blockIdx.y;          // 0..31 (4 high)
    const int b = blockIdx.z;
    const int tid = threadIdx.x;
    const int pix = tid & 63;
    const int grp = tid >> 6;
    const int px = pix & 15, py = pix >> 4;
    const int h = ty * 4 + py, w = tx * 16 + px;

    __shared__ float sm[6 * 18];        // (4+2) x (16+2) halo tile

    float acc[7];
#pragma unroll
    for (int i = 0; i < 7; i++) acc[i] = 0.f;

    const float* xb = x + b * 128 * HW;
    const float* Ub = U + b * HW;

    for (int ci = 0; ci < 129; ci++) {
        if (tid < 108) {
            int r = tid / 18, cl = tid % 18;
            int gy = ty * 4 + r - 1, gx = tx * 16 + cl - 1;
            float v = 0.f;
            if (gy >= 0 && gy < 128 && gx >= 0 && gx < 128) {
                if (ci < 128) v = xb[ci * HW + gy * 128 + gx];
                else {
                    v = Ub[gy * 128 + gx];
                    v = fminf(fmaxf(v, 0.f), 1.f);
                }
            }
            sm[tid] = v;
        }
        __syncthreads();
        float nb[9];
#pragma unroll
        for (int ky = 0; ky < 3; ky++)
#pragma unroll
            for (int kx = 0; kx < 3; kx++)
                nb[ky * 3 + kx] = sm[(py + ky) * 18 + (px + kx)];
#pragma unroll
        for (int t = 0; t < 9; t++) {
            const float* wr = wTom + (ci * 9 + t) * 27 + grp * 7;  // wave-uniform
#pragma unroll
            for (int i = 0; i < 7; i++) acc[i] += nb[t] * wr[i];
        }
        __syncthreads();
    }
    float* omb = om + b * 27 * HW + h * 128 + w;
#pragma unroll
    for (int i = 0; i < 7; i++) {
        int oc = grp * 7 + i;
        if (oc < 27) {
            float v = acc[i] + b_om[oc];
            if (oc >= 18) v = 2.f / (1.f + expf(-v));   // 2*sigmoid -> mask
            omb[oc * HW] = v;
        }
    }
}

// ---------------------------------------------------------------------------
// Kernel B: modulated deformable conv.
// Block: 256 threads = 64 pixels (16x4 tile) x 4 groups of 32 output chans.
// Bilinear corners computed once per (pixel,k); samples shared across all
// output channels via a 16-channel LDS buffer.
// ---------------------------------------------------------------------------
__global__ __launch_bounds__(256) void k_dcn(
    const float* __restrict__ x, const float* __restrict__ om,
    const float* __restrict__ wTd, const float* __restrict__ bdcn,
    float* __restrict__ z)
{
    const int tx = blockIdx.x, ty = blockIdx.y, b = blockIdx.z;
    const int tid = threadIdx.x;
    const int pix = tid & 63, grp = tid >> 6;
    const int px = pix & 15, py = pix >> 4;
    const int h = ty * 4 + py, w = tx * 16 + px;

    __shared__ float sm[16 * 64];   // 16 channels x 64 pixels

    float acc[32];
#pragma unroll
    for (int i = 0; i < 32; i++) acc[i] = 0.f;

    const float* xb = x + b * 128 * HW;
    const float* omb = om + b * 27 * HW + h * 128 + w;

    for (int k = 0; k < 9; k++) {
        float dy = omb[(2 * k) * HW];
        float dx = omb[(2 * k + 1) * HW];
        float m = omb[(18 + k) * HW];
        float fy = (float)(h + k / 3 - 1) + dy;
        float fx = (float)(w + k % 3 - 1) + dx;
        float y0 = floorf(fy), x0 = floorf(fx);
        float ly = fy - y0, lx = fx - x0;
        float hy = 1.f - ly, hx = 1.f - lx;
        float y1 = y0 + 1.f, x1 = x0 + 1.f;
        float vy0 = (y0 >= 0.f && y0 <= 127.f) ? 1.f : 0.f;
        float vy1 = (y1 >= 0.f && y1 <= 127.f) ? 1.f : 0.f;
        float vx0 = (x0 >= 0.f && x0 <= 127.f) ? 1.f : 0.f;
        float vx1 = (x1 >= 0.f && x1 <= 127.f) ? 1.f : 0.f;
        float w00 = hy * hx * vy0 * vx0 * m;
        float w01 = hy * lx * vy0 * vx1 * m;
        float w10 = ly * hx * vy1 * vx0 * m;
        float w11 = ly * lx * vy1 * vx1 * m;
        int iy0 = min(max((int)y0, 0), 127);
        int iy1 = min(max((int)y1, 0), 127);
        int ix0 = min(max((int)x0, 0), 127);
        int ix1 = min(max((int)x1, 0), 127);
        int i00 = iy0 * 128 + ix0, i01 = iy0 * 128 + ix1;
        int i10 = iy1 * 128 + ix0, i11 = iy1 * 128 + ix1;

        for (int ch = 0; ch < 8; ch++) {
#pragma unroll
            for (int j = 0; j < 4; j++) {
                int c = ch * 16 + grp * 4 + j;
                const float* xp = xb + c * HW;
                float v = w00 * xp[i00] + w01 * xp[i01] +
                          w10 * xp[i10] + w11 * xp[i11];
                sm[(grp * 4 + j) * 64 + pix] = v;
            }
            __syncthreads();
            const float* wk = wTd + (k * 128 + ch * 16) * 128 + grp * 32; // uniform
#pragma unroll
            for (int cc = 0; cc < 16; cc++) {
                float v = sm[cc * 64 + pix];
                const float* wr = wk + cc * 128;
#pragma unroll
                for (int i = 0; i < 32; i++) acc[i] += v * wr[i];
            }
            __syncthreads();
        }
    }
    float* zb = z + b * 128 * HW + h * 128 + w;
#pragma unroll
    for (int i = 0; i < 32; i++) {
        int oc = grp * 32 + i;
        zb[oc * HW] = acc[i] + bdcn[oc];
    }
}

// ---------------------------------------------------------------------------
// Kernel C: 128->128 conv3x3.
//  MODE 0: out = relu(conv(in) + bias)                        (conv1)
//  MODE 1: out = relu(xres + (conv(in)+bias) * sigmoid(10*(clipU-0.5)))
// Block: 256 threads = 16x16 pixel tile; blockIdx.z = b*4 + ocg (32 oc each).
// ---------------------------------------------------------------------------
template <int MODE>
__global__ __launch_bounds__(256) void k_conv(
    const float* __restrict__ in, const float* __restrict__ wT,
    const float* __restrict__ bias, float* __restrict__ out,
    const float* __restrict__ xres, const float* __restrict__ U)
{
    const int tx = blockIdx.x, ty = blockIdx.y;
    const int b = blockIdx.z >> 2, ocg = blockIdx.z & 3;
    const int tid = threadIdx.x;
    const int px = tid & 15, py = tid >> 4;
    const int h = ty * 16 + py, w = tx * 16 + px;

    __shared__ float sm[18 * 18];

    float acc[32];
#pragma unroll
    for (int i = 0; i < 32; i++) acc[i] = 0.f;

    const float* inb = in + b * 128 * HW;

    for (int ci = 0; ci < 128; ci++) {
        for (int j = tid; j < 324; j += 256) {
            int r = j / 18, cl = j % 18;
            int gy = ty * 16 + r - 1, gx = tx * 16 + cl - 1;
            float v = 0.f;
            if (gy >= 0 && gy < 128 && gx >= 0 && gx < 128)
                v = inb[ci * HW + gy * 128 + gx];
            sm[j] = v;
        }
        __syncthreads();
        float nb[9];
#pragma unroll
        for (int ky = 0; ky < 3; ky++)
#pragma unroll
            for (int kx = 0; kx < 3; kx++)
                nb[ky * 3 + kx] = sm[(py + ky) * 18 + (px + kx)];
        const float* wc = wT + ci * 9 * 128 + ocg * 32;   // wave-uniform
#pragma unroll
        for (int t = 0; t < 9; t++) {
            const float* wr = wc + t * 128;
#pragma unroll
            for (int i = 0; i < 32; i++) acc[i] += nb[t] * wr[i];
        }
        __syncthreads();
    }

    const int pixoff = h * 128 + w;
    if (MODE == 0) {
        float* ob = out + b * 128 * HW + pixoff;
#pragma unroll
        for (int i = 0; i < 32; i++) {
            int oc = ocg * 32 + i;
            ob[oc * HW] = fmaxf(acc[i] + bias[oc], 0.f);
        }
    } else {
        float u = U[b * HW + pixoff];
        u = fminf(fmaxf(u, 0.f), 1.f);
        float g = 1.f / (1.f + expf(-10.f * (u - 0.5f)));
        const float* xb = xres + b * 128 * HW + pixoff;
        float* ob = out + b * 128 * HW + pixoff;
#pragma unroll
        for (int i = 0; i < 32; i++) {
            int oc = ocg * 32 + i;
            float v = xb[oc * HW] + (acc[i] + bias[oc]) * g;
            ob[oc * HW] = fmaxf(v, 0.f);
        }
    }
}

// ---------------------------------------------------------------------------
extern "C" void kernel_launch(void* const* d_in, const int* in_sizes, int n_in,
                              void* d_out, int out_size, void* d_ws, size_t ws_size,
                              hipStream_t stream)
{
    const float* x     = (const float*)d_in[0];
    const float* U     = (const float*)d_in[1];
    const float* w_om  = (const float*)d_in[2];
    const float* b_om  = (const float*)d_in[3];
    const float* w_dcn = (const float*)d_in[4];
    const float* b_dcn = (const float*)d_in[5];
    const float* w1    = (const float*)d_in[6];
    const float* b1    = (const float*)d_in[7];
    const float* w2    = (const float*)d_in[8];
    const float* b2    = (const float*)d_in[9];
    float* out = (float*)d_out;

    float* ws   = (float*)d_ws;
    float* om   = ws;                   // 4*27*HW      = 1,769,472 f
    float* z    = om + 1769472;         // 4*128*HW     = 8,388,608 f
    float* r1   = z + 8388608;          // 8,388,608 f
    float* wTd  = r1 + 8388608;         // 147,456 f
    float* wT1  = wTd + 147456;
    float* wT2  = wT1 + 147456;
    float* wTom = wT2 + 147456;         // 31,347 f (+pad slack beyond)

    transpose_weights<<<576, 256, 0, stream>>>(w_dcn, w1, w2, w_om,
                                               wTd, wT1, wT2, wTom);
    k_om<<<dim3(8, 32, 4), 256, 0, stream>>>(x, U, wTom, b_om, om);
    k_dcn<<<dim3(8, 32, 4), 256, 0, stream>>>(x, om, wTd, b_dcn, z);
    k_conv<0><<<dim3(8, 8, 16), 256, 0, stream>>>(z, wT1, b1, r1, nullptr, nullptr);
    k_conv<1><<<dim3(8, 8, 16), 256, 0, stream>>>(r1, wT2, b2, out, x, U);
}

// Round 3
// 357.740 us; speedup vs baseline: 6.2613x; 6.2613x over previous
//
#include <hip/hip_runtime.h>
#include <math.h>

typedef unsigned int uint;
typedef unsigned short ushort;
typedef __attribute__((ext_vector_type(8))) __bf16 bf16x8;
typedef __attribute__((ext_vector_type(4))) float f32x4;

#define HW 16384   // 128*128

// ---------- helpers ----------
__device__ __forceinline__ ushort f2bf(float f) {          // fp32 -> bf16 RNE
    uint u = __float_as_uint(f);
    u += 0x7fffu + ((u >> 16) & 1u);
    return (ushort)(u >> 16);
}
// swizzled element index into a [rows][128] bf16 LDS tile.
// chunk = ci/8 (0..15); p = chunk ^ (row&15) keeps 16B alignment and makes
// fragment reads (16 lanes = 16 consecutive rows, same chunk) conflict-free.
__device__ __forceinline__ int swz(int row, int chunk) {
    return row * 128 + ((chunk ^ (row & 15)) << 3);
}
// bilinear blend of 4 packed bf16 pairs -> packed bf16 pair
__device__ __forceinline__ uint blend2(uint a, uint b, uint c, uint d,
                                       float w00, float w01, float w10, float w11) {
    float lo = w00 * __uint_as_float(a << 16) + w01 * __uint_as_float(b << 16)
             + w10 * __uint_as_float(c << 16) + w11 * __uint_as_float(d << 16);
    float hi = w00 * __uint_as_float(a & 0xffff0000u) + w01 * __uint_as_float(b & 0xffff0000u)
             + w10 * __uint_as_float(c & 0xffff0000u) + w11 * __uint_as_float(d & 0xffff0000u);
    uint ul = __float_as_uint(lo); ul += 0x7fffu + ((ul >> 16) & 1u);
    uint uh = __float_as_uint(hi); uh += 0x7fffu + ((uh >> 16) & 1u);
    return (ul >> 16) | ((uh >> 16) << 16);
}

// ---------------------------------------------------------------------------
// Prep 1: weights -> bf16 [tap][oc][ci]; w_om -> [tap][32(pad)][128] + U-col table
// ---------------------------------------------------------------------------
__global__ __launch_bounds__(256) void prep_w(
    const float* __restrict__ wd, const float* __restrict__ w1,
    const float* __restrict__ w2, const float* __restrict__ wom,
    ushort* __restrict__ wdt, ushort* __restrict__ w1t,
    ushort* __restrict__ w2t, ushort* __restrict__ womt,
    float* __restrict__ womu)
{
    int i = blockIdx.x * 256 + threadIdx.x;
    if (i < 147456) {                       // [k][oc][ci], 9*128*128
        int k = i >> 14, oc = (i >> 7) & 127, ci = i & 127;
        int s = (oc * 128 + ci) * 9 + k;
        wdt[i] = f2bf(wd[s]);
        w1t[i] = f2bf(w1[s]);
        w2t[i] = f2bf(w2[s]);
    }
    if (i < 36864) {                        // [k][32][128]
        int k = i >> 12, oc = (i >> 7) & 31, ci = i & 127;
        womt[i] = (oc < 27) ? f2bf(wom[(oc * 129 + ci) * 9 + k]) : (ushort)0;
    }
    if (i < 288) {                          // U-channel column: [k][32]
        int k = i >> 5, oc = i & 31;
        womu[i] = (oc < 27) ? wom[(oc * 129 + 128) * 9 + k] : 0.f;
    }
}

// ---------------------------------------------------------------------------
// Prep 2: x NCHW fp32 -> x_t NHWC bf16, LDS-transposed per (b,h) row.
// ---------------------------------------------------------------------------
__global__ __launch_bounds__(256) void prep_xt(
    const float* __restrict__ x, ushort* __restrict__ xt)
{
    const int h = blockIdx.x, b = blockIdx.y, tid = threadIdx.x;
    __shared__ __align__(16) ushort T[128 * 136];   // [w][c], pad 8
    const int w0 = tid & 127, cg = tid >> 7;
#pragma unroll 4
    for (int it = 0; it < 64; it++) {
        int c = it * 2 + cg;
        float f = x[((size_t)(b * 128 + c)) * HW + h * 128 + w0];
        T[w0 * 136 + c] = f2bf(f);
    }
    __syncthreads();
    const int w1 = tid >> 1, half = tid & 1;
    uint4* dst = (uint4*)(xt + (((size_t)b * HW) + h * 128 + w1) * 128 + half * 64);
    const uint4* src = (const uint4*)&T[w1 * 136 + half * 64];
#pragma unroll
    for (int c8 = 0; c8 < 8; c8++) dst[c8] = src[c8];
}

// ---------------------------------------------------------------------------
// k_om: offset/mask head. MFMA GEMM: M=128 pix (one row), N=32 (27 used),
// K = 9 taps x 128 ci (x part); U channel added in epilogue.
// Output om_t[b][h][w][32] fp32: ch 0..17 offsets, 18..26 mask=2*sigmoid.
// ---------------------------------------------------------------------------
__global__ __launch_bounds__(256, 2) void k_om(
    const ushort* __restrict__ xt, const float* __restrict__ U,
    const ushort* __restrict__ womt, const float* __restrict__ womu,
    const float* __restrict__ bom, float* __restrict__ omt)
{
    const int h = blockIdx.x, b = blockIdx.y, tid = threadIdx.x;
    const int wid = tid >> 6, lane = tid & 63, lq = lane & 15, quad = lane >> 4;
    const int pixbase = wid * 32;

    __shared__ __align__(16) ushort As[128 * 128];   // 32 KB
    __shared__ __align__(16) ushort Bs[32 * 128];    // 8 KB
    __shared__ float U3[3 * 130];
    __shared__ float wu[288];

    f32x4 acc[2][2];
#pragma unroll
    for (int i = 0; i < 2; i++)
#pragma unroll
        for (int j = 0; j < 2; j++)
#pragma unroll
            for (int r = 0; r < 4; r++) acc[i][j][r] = 0.f;

    for (int s = tid; s < 390; s += 256) {
        int r = s / 130, c = s % 130, gy = h - 1 + r, gx = c - 1;
        float v = 0.f;
        if ((unsigned)gy < 128u && (unsigned)gx < 128u) {
            v = U[(size_t)b * HW + gy * 128 + gx];
            v = fminf(fmaxf(v, 0.f), 1.f);
        }
        U3[s] = v;
    }
    for (int s = tid; s < 288; s += 256) wu[s] = womu[s];   // FIX: was `if (tid<288)` with 256 threads -> wu[256..287] uninitialized

    const int row = tid >> 1, half = tid & 1;
    for (int t9 = 0; t9 < 9; t9++) {
        int dy = t9 / 3 - 1, dx = t9 % 3 - 1;
        int gy = h + dy, gx = row + dx;
        if ((unsigned)gy < 128u && (unsigned)gx < 128u) {
            const uint4* src = (const uint4*)(xt + (((size_t)b * HW) + gy * 128 + gx) * 128 + half * 64);
#pragma unroll
            for (int c8 = 0; c8 < 8; c8++) *(uint4*)&As[swz(row, half * 8 + c8)] = src[c8];
        } else {
            uint4 zz = {0, 0, 0, 0};
#pragma unroll
            for (int c8 = 0; c8 < 8; c8++) *(uint4*)&As[swz(row, half * 8 + c8)] = zz;
        }
        if (row < 32) {
            const uint4* src = (const uint4*)(womt + t9 * 4096 + row * 128 + half * 64);
#pragma unroll
            for (int c8 = 0; c8 < 8; c8++) *(uint4*)&Bs[swz(row, half * 8 + c8)] = src[c8];
        }
        __syncthreads();
#pragma unroll
        for (int kk = 0; kk < 4; kk++) {
            int chunk = kk * 4 + quad;
            bf16x8 av[2], bv[2];
#pragma unroll
            for (int i = 0; i < 2; i++) av[i] = *(const bf16x8*)&As[swz(pixbase + i * 16 + lq, chunk)];
#pragma unroll
            for (int j = 0; j < 2; j++) bv[j] = *(const bf16x8*)&Bs[swz(j * 16 + lq, chunk)];
#pragma unroll
            for (int i = 0; i < 2; i++)
#pragma unroll
                for (int j = 0; j < 2; j++)
                    acc[i][j] = __builtin_amdgcn_mfma_f32_16x16x32_bf16(av[i], bv[j], acc[i][j], 0, 0, 0);
        }
        __syncthreads();
    }

    // epilogue: + bias + U-channel conv term; sigmoid for mask channels
#pragma unroll
    for (int j = 0; j < 2; j++) {
        int oc = j * 16 + lq;
        if (oc < 27) {
            float bias = bom[oc];
#pragma unroll
            for (int i = 0; i < 2; i++)
#pragma unroll
                for (int r = 0; r < 4; r++) {
                    int pix = pixbase + i * 16 + quad * 4 + r;
                    float v = acc[i][j][r] + bias;
#pragma unroll
                    for (int t = 0; t < 9; t++)
                        v += U3[(t / 3) * 130 + pix + (t % 3)] * wu[t * 32 + oc];
                    if (oc >= 18) v = 2.f / (1.f + __expf(-v));
                    omt[((size_t)b * HW + h * 128 + pix) * 32 + oc] = v;
                }
        }
    }
}

// ---------------------------------------------------------------------------
// k_dcn: modulated deformable conv as MFMA GEMM.
// A[pix][ci] = mask * bilinear(x_t) per tap (built in LDS), B = wd_t[tap].
// Output z_t NHWC bf16.
// ---------------------------------------------------------------------------
__global__ __launch_bounds__(256, 2) void k_dcn(
    const ushort* __restrict__ xt, const float* __restrict__ omt,
    const ushort* __restrict__ wdt, const float* __restrict__ bdcn,
    ushort* __restrict__ zt)
{
    const int h = blockIdx.x, b = blockIdx.y, tid = threadIdx.x;
    const int wid = tid >> 6, lane = tid & 63, lq = lane & 15, quad = lane >> 4;
    const int pixbase = (wid & 1) * 64, ocbase = (wid >> 1) * 64;

    __shared__ __align__(16) ushort As[128 * 128];
    __shared__ __align__(16) ushort Bs[128 * 128];

    f32x4 acc[4][4];
#pragma unroll
    for (int i = 0; i < 4; i++)
#pragma unroll
        for (int j = 0; j < 4; j++)
#pragma unroll
            for (int r = 0; r < 4; r++) acc[i][j][r] = 0.f;

    const int row = tid >> 1, half = tid & 1;
    const float* omrow = omt + ((size_t)b * HW + h * 128) * 32;
    const ushort* xtb = xt + (size_t)b * HW * 128;

    for (int k = 0; k < 9; k++) {
        // B: weights for tap k
        {
            const uint4* src = (const uint4*)(wdt + (size_t)k * 16384 + row * 128 + half * 64);
#pragma unroll
            for (int c8 = 0; c8 < 8; c8++) *(uint4*)&Bs[swz(row, half * 8 + c8)] = src[c8];
        }
        // corners for pixel `row` (duplicated by the 2 threads sharing the pixel)
        float dyv = omrow[row * 32 + 2 * k];
        float dxv = omrow[row * 32 + 2 * k + 1];
        float m   = omrow[row * 32 + 18 + k];
        float fy = (float)(h + k / 3 - 1) + dyv;
        float fx = (float)(row + k % 3 - 1) + dxv;
        float y0f = floorf(fy), x0f = floorf(fx);
        float ly = fy - y0f, lx = fx - x0f;
        float hy = 1.f - ly, hx = 1.f - lx;
        bool vy0 = (y0f >= 0.f) && (y0f <= 127.f);
        bool vy1 = (y0f >= -1.f) && (y0f <= 126.f);
        bool vx0 = (x0f >= 0.f) && (x0f <= 127.f);
        bool vx1 = (x0f >= -1.f) && (x0f <= 126.f);
        float w00 = (vy0 && vx0) ? hy * hx * m : 0.f;
        float w01 = (vy0 && vx1) ? hy * lx * m : 0.f;
        float w10 = (vy1 && vx0) ? ly * hx * m : 0.f;
        float w11 = (vy1 && vx1) ? ly * lx * m : 0.f;
        int iy0 = min(max((int)y0f, 0), 127);
        int iy1 = min(max((int)y0f + 1, 0), 127);
        int ix0 = min(max((int)x0f, 0), 127);
        int ix1 = min(max((int)x0f + 1, 0), 127);
        const ushort* r00 = xtb + ((size_t)(iy0 * 128 + ix0)) * 128 + half * 64;
        const ushort* r01 = xtb + ((size_t)(iy0 * 128 + ix1)) * 128 + half * 64;
        const ushort* r10 = xtb + ((size_t)(iy1 * 128 + ix0)) * 128 + half * 64;
        const ushort* r11 = xtb + ((size_t)(iy1 * 128 + ix1)) * 128 + half * 64;
#pragma unroll 2
        for (int c8 = 0; c8 < 8; c8++) {
            uint4 q00 = *(const uint4*)(r00 + c8 * 8);
            uint4 q01 = *(const uint4*)(r01 + c8 * 8);
            uint4 q10 = *(const uint4*)(r10 + c8 * 8);
            uint4 q11 = *(const uint4*)(r11 + c8 * 8);
            uint4 st;
            st.x = blend2(q00.x, q01.x, q10.x, q11.x, w00, w01, w10, w11);
            st.y = blend2(q00.y, q01.y, q10.y, q11.y, w00, w01, w10, w11);
            st.z = blend2(q00.z, q01.z, q10.z, q11.z, w00, w01, w10, w11);
            st.w = blend2(q00.w, q01.w, q10.w, q11.w, w00, w01, w10, w11);
            *(uint4*)&As[swz(row, half * 8 + c8)] = st;
        }
        __syncthreads();
#pragma unroll
        for (int kk = 0; kk < 4; kk++) {
            int chunk = kk * 4 + quad;
            bf16x8 av[4], bv[4];
#pragma unroll
            for (int i = 0; i < 4; i++) av[i] = *(const bf16x8*)&As[swz(pixbase + i * 16 + lq, chunk)];
#pragma unroll
            for (int j = 0; j < 4; j++) bv[j] = *(const bf16x8*)&Bs[swz(ocbase + j * 16 + lq, chunk)];
#pragma unroll
            for (int i = 0; i < 4; i++)
#pragma unroll
                for (int j = 0; j < 4; j++)
                    acc[i][j] = __builtin_amdgcn_mfma_f32_16x16x32_bf16(av[i], bv[j], acc[i][j], 0, 0, 0);
        }
        __syncthreads();
    }

    size_t prow = ((size_t)b * HW + h * 128) * 128;
#pragma unroll
    for (int j = 0; j < 4; j++) {
        int oc = ocbase + j * 16 + lq;
        float bias = bdcn[oc];
#pragma unroll
        for (int i = 0; i < 4; i++)
#pragma unroll
            for (int r = 0; r < 4; r++) {
                int pix = pixbase + i * 16 + quad * 4 + r;
                zt[prow + (size_t)pix * 128 + oc] = f2bf(acc[i][j][r] + bias);
            }
    }
}

// ---------------------------------------------------------------------------
// k_conv1: r1 = relu(conv3x3(z) + b1), NHWC bf16 in/out. M=pix, N=oc.
// ---------------------------------------------------------------------------
__global__ __launch_bounds__(256, 2) void k_conv1(
    const ushort* __restrict__ zt, const ushort* __restrict__ w1t,
    const float* __restrict__ b1, ushort* __restrict__ r1t)
{
    const int h = blockIdx.x, b = blockIdx.y, tid = threadIdx.x;
    const int wid = tid >> 6, lane = tid & 63, lq = lane & 15, quad = lane >> 4;
    const int pixbase = (wid & 1) * 64, ocbase = (wid >> 1) * 64;

    __shared__ __align__(16) ushort As[128 * 128];
    __shared__ __align__(16) ushort Bs[128 * 128];

    f32x4 acc[4][4];
#pragma unroll
    for (int i = 0; i < 4; i++)
#pragma unroll
        for (int j = 0; j < 4; j++)
#pragma unroll
            for (int r = 0; r < 4; r++) acc[i][j][r] = 0.f;

    const int row = tid >> 1, half = tid & 1;
    for (int t9 = 0; t9 < 9; t9++) {
        int dy = t9 / 3 - 1, dx = t9 % 3 - 1;
        int gy = h + dy, gx = row + dx;
        if ((unsigned)gy < 128u && (unsigned)gx < 128u) {
            const uint4* src = (const uint4*)(zt + (((size_t)b * HW) + gy * 128 + gx) * 128 + half * 64);
#pragma unroll
            for (int c8 = 0; c8 < 8; c8++) *(uint4*)&As[swz(row, half * 8 + c8)] = src[c8];
        } else {
            uint4 zz = {0, 0, 0, 0};
#pragma unroll
            for (int c8 = 0; c8 < 8; c8++) *(uint4*)&As[swz(row, half * 8 + c8)] = zz;
        }
        {
            const uint4* src = (const uint4*)(w1t + (size_t)t9 * 16384 + row * 128 + half * 64);
#pragma unroll
            for (int c8 = 0; c8 < 8; c8++) *(uint4*)&Bs[swz(row, half * 8 + c8)] = src[c8];
        }
        __syncthreads();
#pragma unroll
        for (int kk = 0; kk < 4; kk++) {
            int chunk = kk * 4 + quad;
            bf16x8 av[4], bv[4];
#pragma unroll
            for (int i = 0; i < 4; i++) av[i] = *(const bf16x8*)&As[swz(pixbase + i * 16 + lq, chunk)];
#pragma unroll
            for (int j = 0; j < 4; j++) bv[j] = *(const bf16x8*)&Bs[swz(ocbase + j * 16 + lq, chunk)];
#pragma unroll
            for (int i = 0; i < 4; i++)
#pragma unroll
                for (int j = 0; j < 4; j++)
                    acc[i][j] = __builtin_amdgcn_mfma_f32_16x16x32_bf16(av[i], bv[j], acc[i][j], 0, 0, 0);
        }
        __syncthreads();
    }

    size_t prow = ((size_t)b * HW + h * 128) * 128;
#pragma unroll
    for (int j = 0; j < 4; j++) {
        int oc = ocbase + j * 16 + lq;
        float bias = b1[oc];
#pragma unroll
        for (int i = 0; i < 4; i++)
#pragma unroll
            for (int r = 0; r < 4; r++) {
                int pix = pixbase + i * 16 + quad * 4 + r;
                r1t[prow + (size_t)pix * 128 + oc] = f2bf(fmaxf(acc[i][j][r] + bias, 0.f));
            }
    }
}

// ---------------------------------------------------------------------------
// k_conv2: out = relu(x + (conv3x3(r1)+b2) * sigmoid(10*(clipU-0.5))).
// Swapped roles: M=oc (A=w2), N=pix (B=r1 rows) so NCHW fp32 stores coalesce.
// ---------------------------------------------------------------------------
__global__ __launch_bounds__(256, 2) void k_conv2(
    const ushort* __restrict__ r1t, const ushort* __restrict__ w2t,
    const float* __restrict__ b2, const float* __restrict__ x,
    const float* __restrict__ U, float* __restrict__ out)
{
    const int h = blockIdx.x, b = blockIdx.y, tid = threadIdx.x;
    const int wid = tid >> 6, lane = tid & 63, lq = lane & 15, quad = lane >> 4;
    const int mbase = (wid & 1) * 64;   // oc
    const int nbase = (wid >> 1) * 64;  // pix

    __shared__ __align__(16) ushort As[128 * 128];  // weights  [oc][ci]
    __shared__ __align__(16) ushort Bs[128 * 128];  // activ.   [pix][ci]

    f32x4 acc[4][4];
#pragma unroll
    for (int i = 0; i < 4; i++)
#pragma unroll
        for (int j = 0; j < 4; j++)
#pragma unroll
            for (int r = 0; r < 4; r++) acc[i][j][r] = 0.f;

    const int row = tid >> 1, half = tid & 1;
    for (int t9 = 0; t9 < 9; t9++) {
        int dy = t9 / 3 - 1, dx = t9 % 3 - 1;
        {
            const uint4* src = (const uint4*)(w2t + (size_t)t9 * 16384 + row * 128 + half * 64);
#pragma unroll
            for (int c8 = 0; c8 < 8; c8++) *(uint4*)&As[swz(row, half * 8 + c8)] = src[c8];
        }
        int gy = h + dy, gx = row + dx;
        if ((unsigned)gy < 128u && (unsigned)gx < 128u) {
            const uint4* src = (const uint4*)(r1t + (((size_t)b * HW) + gy * 128 + gx) * 128 + half * 64);
#pragma unroll
            for (int c8 = 0; c8 < 8; c8++) *(uint4*)&Bs[swz(row, half * 8 + c8)] = src[c8];
        } else {
            uint4 zz = {0, 0, 0, 0};
#pragma unroll
            for (int c8 = 0; c8 < 8; c8++) *(uint4*)&Bs[swz(row, half * 8 + c8)] = zz;
        }
        __syncthreads();
#pragma unroll
        for (int kk = 0; kk < 4; kk++) {
            int chunk = kk * 4 + quad;
            bf16x8 av[4], bv[4];
#pragma unroll
            for (int i = 0; i < 4; i++) av[i] = *(const bf16x8*)&As[swz(mbase + i * 16 + lq, chunk)];
#pragma unroll
            for (int j = 0; j < 4; j++) bv[j] = *(const bf16x8*)&Bs[swz(nbase + j * 16 + lq, chunk)];
#pragma unroll
            for (int i = 0; i < 4; i++)
#pragma unroll
                for (int j = 0; j < 4; j++)
                    acc[i][j] = __builtin_amdgcn_mfma_f32_16x16x32_bf16(av[i], bv[j], acc[i][j], 0, 0, 0);
        }
        __syncthreads();
    }

#pragma unroll
    for (int j = 0; j < 4; j++) {
        int pix = nbase + j * 16 + lq;
        float u = U[(size_t)b * HW + h * 128 + pix];
        u = fminf(fmaxf(u, 0.f), 1.f);
        float g = 1.f / (1.f + __expf(-10.f * (u - 0.5f)));
#pragma unroll
        for (int i = 0; i < 4; i++) {
            f32x4 b4 = *(const f32x4*)&b2[mbase + i * 16 + quad * 4];
#pragma unroll
            for (int r = 0; r < 4; r++) {
                int oc = mbase + i * 16 + quad * 4 + r;
                size_t idx = ((size_t)(b * 128 + oc)) * HW + h * 128 + pix;
                float v = acc[i][j][r] + b4[r];
                out[idx] = fmaxf(x[idx] + v * g, 0.f);
            }
        }
    }
}

// ---------------------------------------------------------------------------
extern "C" void kernel_launch(void* const* d_in, const int* in_sizes, int n_in,
                              void* d_out, int out_size, void* d_ws, size_t ws_size,
                              hipStream_t stream)
{
    const float* x     = (const float*)d_in[0];
    const float* U     = (const float*)d_in[1];
    const float* w_om  = (const float*)d_in[2];
    const float* b_om  = (const float*)d_in[3];
    const float* w_dcn = (const float*)d_in[4];
    const float* b_dcn = (const float*)d_in[5];
    const float* w1    = (const float*)d_in[6];
    const float* b1    = (const float*)d_in[7];
    const float* w2    = (const float*)d_in[8];
    const float* b2    = (const float*)d_in[9];
    float* out = (float*)d_out;

    char* p = (char*)d_ws;
    ushort* xt   = (ushort*)p; p += (size_t)4 * HW * 128 * 2;   // 16.78 MB
    ushort* zt   = (ushort*)p; p += (size_t)4 * HW * 128 * 2;
    ushort* r1t  = (ushort*)p; p += (size_t)4 * HW * 128 * 2;
    float*  omt  = (float*)p;  p += (size_t)4 * HW * 32 * 4;    // 8.39 MB
    ushort* wdt  = (ushort*)p; p += 147456 * 2;
    ushort* w1t  = (ushort*)p; p += 147456 * 2;
    ushort* w2t  = (ushort*)p; p += 147456 * 2;
    ushort* womt = (ushort*)p; p += 36864 * 2;
    float*  womu = (float*)p;  p += 288 * 4;

    prep_w<<<576, 256, 0, stream>>>(w_dcn, w1, w2, w_om, wdt, w1t, w2t, womt, womu);
    prep_xt<<<dim3(128, 4), 256, 0, stream>>>(x, xt);
    k_om<<<dim3(128, 4), 256, 0, stream>>>(xt, U, womt, womu, b_om, omt);
    k_dcn<<<dim3(128, 4), 256, 0, stream>>>(xt, omt, wdt, b_dcn, zt);
    k_conv1<<<dim3(128, 4), 256, 0, stream>>>(zt, w1t, b1, r1t);
    k_conv2<<<dim3(128, 4), 256, 0, stream>>>(r1t, w2t, b2, x, U, out);
}

// Round 4
// 309.190 us; speedup vs baseline: 7.2445x; 1.1570x over previous
//
#include <hip/hip_runtime.h>
#include <math.h>

typedef unsigned int uint;
typedef unsigned short ushort;
typedef __attribute__((ext_vector_type(8))) __bf16 bf16x8;
typedef __attribute__((ext_vector_type(4))) float f32x4;

#define HW 16384   // 128*128

// ---------- helpers ----------
__device__ __forceinline__ ushort f2bf(float f) {          // fp32 -> bf16 RNE
    uint u = __float_as_uint(f);
    u += 0x7fffu + ((u >> 16) & 1u);
    return (ushort)(u >> 16);
}
// XCD-affinity swizzle: 512 blocks, dispatch round-robins XCDs by linear id.
// Remap so XCD k owns 64 contiguous (b,h) rows -> per-XCD L2 working set
// ~3.7 MB < 4 MB, and producer/consumer kernels share the same mapping.
__device__ __forceinline__ void bhmap(int& b, int& h) {
    int lin = blockIdx.y * (int)gridDim.x + blockIdx.x;
    int n = (lin & 7) * 64 + (lin >> 3);
    h = n & 127;
    b = n >> 7;
}
// swizzled element index into a [rows][128] bf16 LDS tile.
// chunk = ci/8 (0..15); chunk ^ (row&15) keeps 16B alignment and makes
// fragment reads (16 lanes = 16 consecutive rows, same chunk) conflict-free.
__device__ __forceinline__ int swz(int row, int chunk) {
    return row * 128 + ((chunk ^ (row & 15)) << 3);
}
// bilinear blend of 4 packed bf16 pairs -> packed bf16 pair
__device__ __forceinline__ uint blend2(uint a, uint b, uint c, uint d,
                                       float w00, float w01, float w10, float w11) {
    float lo = w00 * __uint_as_float(a << 16) + w01 * __uint_as_float(b << 16)
             + w10 * __uint_as_float(c << 16) + w11 * __uint_as_float(d << 16);
    float hi = w00 * __uint_as_float(a & 0xffff0000u) + w01 * __uint_as_float(b & 0xffff0000u)
             + w10 * __uint_as_float(c & 0xffff0000u) + w11 * __uint_as_float(d & 0xffff0000u);
    uint ul = __float_as_uint(lo); ul += 0x7fffu + ((ul >> 16) & 1u);
    uint uh = __float_as_uint(hi); uh += 0x7fffu + ((uh >> 16) & 1u);
    return (ul >> 16) | ((uh >> 16) << 16);
}

// ---------------------------------------------------------------------------
// Prep 1: weights -> bf16 [tap][oc][ci]; w_om -> [tap][32(pad)][128] + U-col table
// ---------------------------------------------------------------------------
__global__ __launch_bounds__(256) void prep_w(
    const float* __restrict__ wd, const float* __restrict__ w1,
    const float* __restrict__ w2, const float* __restrict__ wom,
    ushort* __restrict__ wdt, ushort* __restrict__ w1t,
    ushort* __restrict__ w2t, ushort* __restrict__ womt,
    float* __restrict__ womu)
{
    int i = blockIdx.x * 256 + threadIdx.x;
    if (i < 147456) {                       // [k][oc][ci], 9*128*128
        int k = i >> 14, oc = (i >> 7) & 127, ci = i & 127;
        int s = (oc * 128 + ci) * 9 + k;
        wdt[i] = f2bf(wd[s]);
        w1t[i] = f2bf(w1[s]);
        w2t[i] = f2bf(w2[s]);
    }
    if (i < 36864) {                        // [k][32][128]
        int k = i >> 12, oc = (i >> 7) & 31, ci = i & 127;
        womt[i] = (oc < 27) ? f2bf(wom[(oc * 129 + ci) * 9 + k]) : (ushort)0;
    }
    if (i < 288) {                          // U-channel column: [k][32]
        int k = i >> 5, oc = i & 31;
        womu[i] = (oc < 27) ? wom[(oc * 129 + 128) * 9 + k] : 0.f;
    }
}

// ---------------------------------------------------------------------------
// Prep 2: x NCHW fp32 -> x_t NHWC bf16, LDS-transposed per (b,h) row.
// ---------------------------------------------------------------------------
__global__ __launch_bounds__(256) void prep_xt(
    const float* __restrict__ x, ushort* __restrict__ xt)
{
    int b, h; bhmap(b, h);
    const int tid = threadIdx.x;
    __shared__ __align__(16) ushort T[128 * 136];   // [w][c], pad 8
    const int w0 = tid & 127, cg = tid >> 7;
#pragma unroll 4
    for (int it = 0; it < 64; it++) {
        int c = it * 2 + cg;
        float f = x[((size_t)(b * 128 + c)) * HW + h * 128 + w0];
        T[w0 * 136 + c] = f2bf(f);
    }
    __syncthreads();
    const int w1 = tid >> 1, half = tid & 1;
    uint4* dst = (uint4*)(xt + (((size_t)b * HW) + h * 128 + w1) * 128 + half * 64);
    const uint4* src = (const uint4*)&T[w1 * 136 + half * 64];
#pragma unroll
    for (int c8 = 0; c8 < 8; c8++) dst[c8] = src[c8];
}

// ---------------------------------------------------------------------------
// k_om: offset/mask head. MFMA GEMM: M=128 pix (one row), N=32 (27 used),
// K = 9 taps x 128 ci (x part); U channel added in epilogue.
// Output om_t[b][h][w][32] fp32: ch 0..17 offsets, 18..26 mask=2*sigmoid.
// ---------------------------------------------------------------------------
__global__ __launch_bounds__(256, 2) void k_om(
    const ushort* __restrict__ xt, const float* __restrict__ U,
    const ushort* __restrict__ womt, const float* __restrict__ womu,
    const float* __restrict__ bom, float* __restrict__ omt)
{
    int b, h; bhmap(b, h);
    const int tid = threadIdx.x;
    const int wid = tid >> 6, lane = tid & 63, lq = lane & 15, quad = lane >> 4;
    const int pixbase = wid * 32;

    __shared__ __align__(16) ushort As[128 * 128];   // 32 KB
    __shared__ __align__(16) ushort Bs[32 * 128];    // 8 KB
    __shared__ float U3[3 * 130];
    __shared__ float wu[288];

    f32x4 acc[2][2];
#pragma unroll
    for (int i = 0; i < 2; i++)
#pragma unroll
        for (int j = 0; j < 2; j++)
#pragma unroll
            for (int r = 0; r < 4; r++) acc[i][j][r] = 0.f;

    for (int s = tid; s < 390; s += 256) {
        int r = s / 130, c = s % 130, gy = h - 1 + r, gx = c - 1;
        float v = 0.f;
        if ((unsigned)gy < 128u && (unsigned)gx < 128u) {
            v = U[(size_t)b * HW + gy * 128 + gx];
            v = fminf(fmaxf(v, 0.f), 1.f);
        }
        U3[s] = v;
    }
    for (int s = tid; s < 288; s += 256) wu[s] = womu[s];

    const int row = tid >> 1, half = tid & 1;
    for (int t9 = 0; t9 < 9; t9++) {
        int dy = t9 / 3 - 1, dx = t9 % 3 - 1;
        int gy = h + dy, gx = row + dx;
        if ((unsigned)gy < 128u && (unsigned)gx < 128u) {
            const uint4* src = (const uint4*)(xt + (((size_t)b * HW) + gy * 128 + gx) * 128 + half * 64);
#pragma unroll
            for (int c8 = 0; c8 < 8; c8++) *(uint4*)&As[swz(row, half * 8 + c8)] = src[c8];
        } else {
            uint4 zz = {0, 0, 0, 0};
#pragma unroll
            for (int c8 = 0; c8 < 8; c8++) *(uint4*)&As[swz(row, half * 8 + c8)] = zz;
        }
        if (row < 32) {
            const uint4* src = (const uint4*)(womt + t9 * 4096 + row * 128 + half * 64);
#pragma unroll
            for (int c8 = 0; c8 < 8; c8++) *(uint4*)&Bs[swz(row, half * 8 + c8)] = src[c8];
        }
        __syncthreads();
#pragma unroll
        for (int kk = 0; kk < 4; kk++) {
            int chunk = kk * 4 + quad;
            bf16x8 av[2], bv[2];
#pragma unroll
            for (int i = 0; i < 2; i++) av[i] = *(const bf16x8*)&As[swz(pixbase + i * 16 + lq, chunk)];
#pragma unroll
            for (int j = 0; j < 2; j++) bv[j] = *(const bf16x8*)&Bs[swz(j * 16 + lq, chunk)];
#pragma unroll
            for (int i = 0; i < 2; i++)
#pragma unroll
                for (int j = 0; j < 2; j++)
                    acc[i][j] = __builtin_amdgcn_mfma_f32_16x16x32_bf16(av[i], bv[j], acc[i][j], 0, 0, 0);
        }
        __syncthreads();
    }

    // epilogue: + bias + U-channel conv term; sigmoid for mask channels
#pragma unroll
    for (int j = 0; j < 2; j++) {
        int oc = j * 16 + lq;
        if (oc < 27) {
            float bias = bom[oc];
#pragma unroll
            for (int i = 0; i < 2; i++)
#pragma unroll
                for (int r = 0; r < 4; r++) {
                    int pix = pixbase + i * 16 + quad * 4 + r;
                    float v = acc[i][j][r] + bias;
#pragma unroll
                    for (int t = 0; t < 9; t++)
                        v += U3[(t / 3) * 130 + pix + (t % 3)] * wu[t * 32 + oc];
                    if (oc >= 18) v = 2.f / (1.f + __expf(-v));
                    omt[((size_t)b * HW + h * 128 + pix) * 32 + oc] = v;
                }
        }
    }
}

// ---------------------------------------------------------------------------
// k_dcn: modulated deformable conv as MFMA GEMM.
// A[pix][ci] = mask * bilinear(x_t) per tap (built in LDS), B = wd_t[tap].
// Output z_t NHWC bf16.
// ---------------------------------------------------------------------------
__global__ __launch_bounds__(256, 2) void k_dcn(
    const ushort* __restrict__ xt, const float* __restrict__ omt,
    const ushort* __restrict__ wdt, const float* __restrict__ bdcn,
    ushort* __restrict__ zt)
{
    int b, h; bhmap(b, h);
    const int tid = threadIdx.x;
    const int wid = tid >> 6, lane = tid & 63, lq = lane & 15, quad = lane >> 4;
    const int pixbase = (wid & 1) * 64, ocbase = (wid >> 1) * 64;

    __shared__ __align__(16) ushort As[128 * 128];
    __shared__ __align__(16) ushort Bs[128 * 128];

    f32x4 acc[4][4];
#pragma unroll
    for (int i = 0; i < 4; i++)
#pragma unroll
        for (int j = 0; j < 4; j++)
#pragma unroll
            for (int r = 0; r < 4; r++) acc[i][j][r] = 0.f;

    const int row = tid >> 1, half = tid & 1;
    const float* omrow = omt + ((size_t)b * HW + h * 128) * 32;
    const ushort* xtb = xt + (size_t)b * HW * 128;

    for (int k = 0; k < 9; k++) {
        // B: weights for tap k
        {
            const uint4* src = (const uint4*)(wdt + (size_t)k * 16384 + row * 128 + half * 64);
#pragma unroll
            for (int c8 = 0; c8 < 8; c8++) *(uint4*)&Bs[swz(row, half * 8 + c8)] = src[c8];
        }
        // corners for pixel `row` (duplicated by the 2 threads sharing the pixel)
        float dyv = omrow[row * 32 + 2 * k];
        float dxv = omrow[row * 32 + 2 * k + 1];
        float m   = omrow[row * 32 + 18 + k];
        float fy = (float)(h + k / 3 - 1) + dyv;
        float fx = (float)(row + k % 3 - 1) + dxv;
        float y0f = floorf(fy), x0f = floorf(fx);
        float ly = fy - y0f, lx = fx - x0f;
        float hy = 1.f - ly, hx = 1.f - lx;
        bool vy0 = (y0f >= 0.f) && (y0f <= 127.f);
        bool vy1 = (y0f >= -1.f) && (y0f <= 126.f);
        bool vx0 = (x0f >= 0.f) && (x0f <= 127.f);
        bool vx1 = (x0f >= -1.f) && (x0f <= 126.f);
        float w00 = (vy0 && vx0) ? hy * hx * m : 0.f;
        float w01 = (vy0 && vx1) ? hy * lx * m : 0.f;
        float w10 = (vy1 && vx0) ? ly * hx * m : 0.f;
        float w11 = (vy1 && vx1) ? ly * lx * m : 0.f;
        int iy0 = min(max((int)y0f, 0), 127);
        int iy1 = min(max((int)y0f + 1, 0), 127);
        int ix0 = min(max((int)x0f, 0), 127);
        int ix1 = min(max((int)x0f + 1, 0), 127);
        const ushort* r00 = xtb + ((size_t)(iy0 * 128 + ix0)) * 128 + half * 64;
        const ushort* r01 = xtb + ((size_t)(iy0 * 128 + ix1)) * 128 + half * 64;
        const ushort* r10 = xtb + ((size_t)(iy1 * 128 + ix0)) * 128 + half * 64;
        const ushort* r11 = xtb + ((size_t)(iy1 * 128 + ix1)) * 128 + half * 64;
#pragma unroll 4
        for (int c8 = 0; c8 < 8; c8++) {
            uint4 q00 = *(const uint4*)(r00 + c8 * 8);
            uint4 q01 = *(const uint4*)(r01 + c8 * 8);
            uint4 q10 = *(const uint4*)(r10 + c8 * 8);
            uint4 q11 = *(const uint4*)(r11 + c8 * 8);
            uint4 st;
            st.x = blend2(q00.x, q01.x, q10.x, q11.x, w00, w01, w10, w11);
            st.y = blend2(q00.y, q01.y, q10.y, q11.y, w00, w01, w10, w11);
            st.z = blend2(q00.z, q01.z, q10.z, q11.z, w00, w01, w10, w11);
            st.w = blend2(q00.w, q01.w, q10.w, q11.w, w00, w01, w10, w11);
            *(uint4*)&As[swz(row, half * 8 + c8)] = st;
        }
        __syncthreads();
#pragma unroll
        for (int kk = 0; kk < 4; kk++) {
            int chunk = kk * 4 + quad;
            bf16x8 av[4], bv[4];
#pragma unroll
            for (int i = 0; i < 4; i++) av[i] = *(const bf16x8*)&As[swz(pixbase + i * 16 + lq, chunk)];
#pragma unroll
            for (int j = 0; j < 4; j++) bv[j] = *(const bf16x8*)&Bs[swz(ocbase + j * 16 + lq, chunk)];
#pragma unroll
            for (int i = 0; i < 4; i++)
#pragma unroll
                for (int j = 0; j < 4; j++)
                    acc[i][j] = __builtin_amdgcn_mfma_f32_16x16x32_bf16(av[i], bv[j], acc[i][j], 0, 0, 0);
        }
        __syncthreads();
    }

    size_t prow = ((size_t)b * HW + h * 128) * 128;
#pragma unroll
    for (int j = 0; j < 4; j++) {
        int oc = ocbase + j * 16 + lq;
        float bias = bdcn[oc];
#pragma unroll
        for (int i = 0; i < 4; i++)
#pragma unroll
            for (int r = 0; r < 4; r++) {
                int pix = pixbase + i * 16 + quad * 4 + r;
                zt[prow + (size_t)pix * 128 + oc] = f2bf(acc[i][j][r] + bias);
            }
    }
}

// ---------------------------------------------------------------------------
// k_conv1: r1 = relu(conv3x3(z) + b1), NHWC bf16 in/out. M=pix, N=oc.
// ---------------------------------------------------------------------------
__global__ __launch_bounds__(256, 2) void k_conv1(
    const ushort* __restrict__ zt, const ushort* __restrict__ w1t,
    const float* __restrict__ b1, ushort* __restrict__ r1t)
{
    int b, h; bhmap(b, h);
    const int tid = threadIdx.x;
    const int wid = tid >> 6, lane = tid & 63, lq = lane & 15, quad = lane >> 4;
    const int pixbase = (wid & 1) * 64, ocbase = (wid >> 1) * 64;

    __shared__ __align__(16) ushort As[128 * 128];
    __shared__ __align__(16) ushort Bs[128 * 128];

    f32x4 acc[4][4];
#pragma unroll
    for (int i = 0; i < 4; i++)
#pragma unroll
        for (int j = 0; j < 4; j++)
#pragma unroll
            for (int r = 0; r < 4; r++) acc[i][j][r] = 0.f;

    const int row = tid >> 1, half = tid & 1;
    for (int t9 = 0; t9 < 9; t9++) {
        int dy = t9 / 3 - 1, dx = t9 % 3 - 1;
        int gy = h + dy, gx = row + dx;
        if ((unsigned)gy < 128u && (unsigned)gx < 128u) {
            const uint4* src = (const uint4*)(zt + (((size_t)b * HW) + gy * 128 + gx) * 128 + half * 64);
#pragma unroll
            for (int c8 = 0; c8 < 8; c8++) *(uint4*)&As[swz(row, half * 8 + c8)] = src[c8];
        } else {
            uint4 zz = {0, 0, 0, 0};
#pragma unroll
            for (int c8 = 0; c8 < 8; c8++) *(uint4*)&As[swz(row, half * 8 + c8)] = zz;
        }
        {
            const uint4* src = (const uint4*)(w1t + (size_t)t9 * 16384 + row * 128 + half * 64);
#pragma unroll
            for (int c8 = 0; c8 < 8; c8++) *(uint4*)&Bs[swz(row, half * 8 + c8)] = src[c8];
        }
        __syncthreads();
#pragma unroll
        for (int kk = 0; kk < 4; kk++) {
            int chunk = kk * 4 + quad;
            bf16x8 av[4], bv[4];
#pragma unroll
            for (int i = 0; i < 4; i++) av[i] = *(const bf16x8*)&As[swz(pixbase + i * 16 + lq, chunk)];
#pragma unroll
            for (int j = 0; j < 4; j++) bv[j] = *(const bf16x8*)&Bs[swz(ocbase + j * 16 + lq, chunk)];
#pragma unroll
            for (int i = 0; i < 4; i++)
#pragma unroll
                for (int j = 0; j < 4; j++)
                    acc[i][j] = __builtin_amdgcn_mfma_f32_16x16x32_bf16(av[i], bv[j], acc[i][j], 0, 0, 0);
        }
        __syncthreads();
    }

    size_t prow = ((size_t)b * HW + h * 128) * 128;
#pragma unroll
    for (int j = 0; j < 4; j++) {
        int oc = ocbase + j * 16 + lq;
        float bias = b1[oc];
#pragma unroll
        for (int i = 0; i < 4; i++)
#pragma unroll
            for (int r = 0; r < 4; r++) {
                int pix = pixbase + i * 16 + quad * 4 + r;
                r1t[prow + (size_t)pix * 128 + oc] = f2bf(fmaxf(acc[i][j][r] + bias, 0.f));
            }
    }
}

// ---------------------------------------------------------------------------
// k_conv2: out = relu(x + (conv3x3(r1)+b2) * sigmoid(10*(clipU-0.5))).
// Swapped roles: M=oc (A=w2), N=pix (B=r1 rows) so NCHW fp32 stores coalesce.
// ---------------------------------------------------------------------------
__global__ __launch_bounds__(256, 2) void k_conv2(
    const ushort* __restrict__ r1t, const ushort* __restrict__ w2t,
    const float* __restrict__ b2, const float* __restrict__ x,
    const float* __restrict__ U, float* __restrict__ out)
{
    int b, h; bhmap(b, h);
    const int tid = threadIdx.x;
    const int wid = tid >> 6, lane = tid & 63, lq = lane & 15, quad = lane >> 4;
    const int mbase = (wid & 1) * 64;   // oc
    const int nbase = (wid >> 1) * 64;  // pix

    __shared__ __align__(16) ushort As[128 * 128];  // weights  [oc][ci]
    __shared__ __align__(16) ushort Bs[128 * 128];  // activ.   [pix][ci]

    f32x4 acc[4][4];
#pragma unroll
    for (int i = 0; i < 4; i++)
#pragma unroll
        for (int j = 0; j < 4; j++)
#pragma unroll
            for (int r = 0; r < 4; r++) acc[i][j][r] = 0.f;

    const int row = tid >> 1, half = tid & 1;
    for (int t9 = 0; t9 < 9; t9++) {
        int dy = t9 / 3 - 1, dx = t9 % 3 - 1;
        {
            const uint4* src = (const uint4*)(w2t + (size_t)t9 * 16384 + row * 128 + half * 64);
#pragma unroll
            for (int c8 = 0; c8 < 8; c8++) *(uint4*)&As[swz(row, half * 8 + c8)] = src[c8];
        }
        int gy = h + dy, gx = row + dx;
        if ((unsigned)gy < 128u && (unsigned)gx < 128u) {
            const uint4* src = (const uint4*)(r1t + (((size_t)b * HW) + gy * 128 + gx) * 128 + half * 64);
#pragma unroll
            for (int c8 = 0; c8 < 8; c8++) *(uint4*)&Bs[swz(row, half * 8 + c8)] = src[c8];
        } else {
            uint4 zz = {0, 0, 0, 0};
#pragma unroll
            for (int c8 = 0; c8 < 8; c8++) *(uint4*)&Bs[swz(row, half * 8 + c8)] = zz;
        }
        __syncthreads();
#pragma unroll
        for (int kk = 0; kk < 4; kk++) {
            int chunk = kk * 4 + quad;
            bf16x8 av[4], bv[4];
#pragma unroll
            for (int i = 0; i < 4; i++) av[i] = *(const bf16x8*)&As[swz(mbase + i * 16 + lq, chunk)];
#pragma unroll
            for (int j = 0; j < 4; j++) bv[j] = *(const bf16x8*)&Bs[swz(nbase + j * 16 + lq, chunk)];
#pragma unroll
            for (int i = 0; i < 4; i++)
#pragma unroll
                for (int j = 0; j < 4; j++)
                    acc[i][j] = __builtin_amdgcn_mfma_f32_16x16x32_bf16(av[i], bv[j], acc[i][j], 0, 0, 0);
        }
        __syncthreads();
    }

#pragma unroll
    for (int j = 0; j < 4; j++) {
        int pix = nbase + j * 16 + lq;
        float u = U[(size_t)b * HW + h * 128 + pix];
        u = fminf(fmaxf(u, 0.f), 1.f);
        float g = 1.f / (1.f + __expf(-10.f * (u - 0.5f)));
#pragma unroll
        for (int i = 0; i < 4; i++) {
            f32x4 b4 = *(const f32x4*)&b2[mbase + i * 16 + quad * 4];
#pragma unroll
            for (int r = 0; r < 4; r++) {
                int oc = mbase + i * 16 + quad * 4 + r;
                size_t idx = ((size_t)(b * 128 + oc)) * HW + h * 128 + pix;
                float v = acc[i][j][r] + b4[r];
                out[idx] = fmaxf(x[idx] + v * g, 0.f);
            }
        }
    }
}

// ---------------------------------------------------------------------------
extern "C" void kernel_launch(void* const* d_in, const int* in_sizes, int n_in,
                              void* d_out, int out_size, void* d_ws, size_t ws_size,
                              hipStream_t stream)
{
    const float* x     = (const float*)d_in[0];
    const float* U     = (const float*)d_in[1];
    const float* w_om  = (const float*)d_in[2];
    const float* b_om  = (const float*)d_in[3];
    const float* w_dcn = (const float*)d_in[4];
    const float* b_dcn = (const float*)d_in[5];
    const float* w1    = (const float*)d_in[6];
    const float* b1    = (const float*)d_in[7];
    const float* w2    = (const float*)d_in[8];
    const float* b2    = (const float*)d_in[9];
    float* out = (float*)d_out;

    char* p = (char*)d_ws;
    ushort* xt   = (ushort*)p; p += (size_t)4 * HW * 128 * 2;   // 16.78 MB
    ushort* zt   = (ushort*)p; p += (size_t)4 * HW * 128 * 2;
    ushort* r1t  = (ushort*)p; p += (size_t)4 * HW * 128 * 2;
    float*  omt  = (float*)p;  p += (size_t)4 * HW * 32 * 4;    // 8.39 MB
    ushort* wdt  = (ushort*)p; p += 147456 * 2;
    ushort* w1t  = (ushort*)p; p += 147456 * 2;
    ushort* w2t  = (ushort*)p; p += 147456 * 2;
    ushort* womt = (ushort*)p; p += 36864 * 2;
    float*  womu = (float*)p;  p += 288 * 4;

    prep_w<<<576, 256, 0, stream>>>(w_dcn, w1, w2, w_om, wdt, w1t, w2t, womt, womu);
    prep_xt<<<dim3(128, 4), 256, 0, stream>>>(x, xt);
    k_om<<<dim3(128, 4), 256, 0, stream>>>(xt, U, womt, womu, b_om, omt);
    k_dcn<<<dim3(128, 4), 256, 0, stream>>>(xt, omt, wdt, b_dcn, zt);
    k_conv1<<<dim3(128, 4), 256, 0, stream>>>(zt, w1t, b1, r1t);
    k_conv2<<<dim3(128, 4), 256, 0, stream>>>(r1t, w2t, b2, x, U, out);
}

// Round 5
// 276.011 us; speedup vs baseline: 8.1154x; 1.1202x over previous
//
#include <hip/hip_runtime.h>
#include <math.h>

typedef unsigned int uint;
typedef unsigned short ushort;
typedef __attribute__((ext_vector_type(8))) __bf16 bf16x8;
typedef __attribute__((ext_vector_type(4))) float f32x4;

#define HW 16384   // 128*128

// ---------- helpers ----------
__device__ __forceinline__ ushort f2bf(float f) {          // fp32 -> bf16 RNE
    uint u = __float_as_uint(f);
    u += 0x7fffu + ((u >> 16) & 1u);
    return (ushort)(u >> 16);
}
// XCD-affinity swizzle: 512 blocks, dispatch round-robins XCDs by linear id.
// Remap so XCD k owns 64 contiguous (b,h) rows -> per-XCD L2 working set
// < 4 MB, and producer/consumer kernels share the same mapping.
__device__ __forceinline__ void bhmap(int& b, int& h) {
    int lin = blockIdx.y * (int)gridDim.x + blockIdx.x;
    int n = (lin & 7) * 64 + (lin >> 3);
    h = n & 127;
    b = n >> 7;
}
// swizzled element index into a [rows][128] bf16 LDS tile.
__device__ __forceinline__ int swz(int row, int chunk) {
    return row * 128 + ((chunk ^ (row & 15)) << 3);
}
// bilinear blend of 4 packed bf16 pairs -> packed bf16 pair
__device__ __forceinline__ uint blend2(uint a, uint b, uint c, uint d,
                                       float w00, float w01, float w10, float w11) {
    float lo = w00 * __uint_as_float(a << 16) + w01 * __uint_as_float(b << 16)
             + w10 * __uint_as_float(c << 16) + w11 * __uint_as_float(d << 16);
    float hi = w00 * __uint_as_float(a & 0xffff0000u) + w01 * __uint_as_float(b & 0xffff0000u)
             + w10 * __uint_as_float(c & 0xffff0000u) + w11 * __uint_as_float(d & 0xffff0000u);
    uint ul = __float_as_uint(lo); ul += 0x7fffu + ((ul >> 16) & 1u);
    uint uh = __float_as_uint(hi); uh += 0x7fffu + ((uh >> 16) & 1u);
    return (ul >> 16) | ((uh >> 16) << 16);
}

// ---------------------------------------------------------------------------
// Prep 1: weights -> bf16 [tap][oc][ci]; w_om -> [tap][32(pad)][128] + U-col table
// ---------------------------------------------------------------------------
__global__ __launch_bounds__(256) void prep_w(
    const float* __restrict__ wd, const float* __restrict__ w1,
    const float* __restrict__ w2, const float* __restrict__ wom,
    ushort* __restrict__ wdt, ushort* __restrict__ w1t,
    ushort* __restrict__ w2t, ushort* __restrict__ womt,
    float* __restrict__ womu)
{
    int i = blockIdx.x * 256 + threadIdx.x;
    if (i < 147456) {                       // [k][oc][ci], 9*128*128
        int k = i >> 14, oc = (i >> 7) & 127, ci = i & 127;
        int s = (oc * 128 + ci) * 9 + k;
        wdt[i] = f2bf(wd[s]);
        w1t[i] = f2bf(w1[s]);
        w2t[i] = f2bf(w2[s]);
    }
    if (i < 36864) {                        // [k][32][128]
        int k = i >> 12, oc = (i >> 7) & 31, ci = i & 127;
        womt[i] = (oc < 27) ? f2bf(wom[(oc * 129 + ci) * 9 + k]) : (ushort)0;
    }
    if (i < 288) {                          // U-channel column: [k][32]
        int k = i >> 5, oc = i & 31;
        womu[i] = (oc < 27) ? wom[(oc * 129 + 128) * 9 + k] : 0.f;
    }
}

// ---------------------------------------------------------------------------
// Prep 2: x NCHW fp32 -> x_t NHWC bf16, LDS-transposed per (b,h) row.
// ---------------------------------------------------------------------------
__global__ __launch_bounds__(256) void prep_xt(
    const float* __restrict__ x, ushort* __restrict__ xt)
{
    int b, h; bhmap(b, h);
    const int tid = threadIdx.x;
    __shared__ __align__(16) ushort T[128 * 136];   // [w][c], pad 8
    const int w0 = tid & 127, cg = tid >> 7;
#pragma unroll 4
    for (int it = 0; it < 64; it++) {
        int c = it * 2 + cg;
        float f = x[((size_t)(b * 128 + c)) * HW + h * 128 + w0];
        T[w0 * 136 + c] = f2bf(f);
    }
    __syncthreads();
    const int w1 = tid >> 1, half = tid & 1;
    uint4* dst = (uint4*)(xt + (((size_t)b * HW) + h * 128 + w1) * 128 + half * 64);
    const uint4* src = (const uint4*)&T[w1 * 136 + half * 64];
#pragma unroll
    for (int c8 = 0; c8 < 8; c8++) dst[c8] = src[c8];
}

// ---------------------------------------------------------------------------
// k_om: offset/mask head. MFMA GEMM: M=128 pix (one row), N=32 (27 used),
// K = 9 taps x 128 ci (x part); U channel added in epilogue.
// Output om_t[b][h][w][32] fp32: ch 0..17 offsets, 18..26 mask=2*sigmoid.
// ---------------------------------------------------------------------------
__global__ __launch_bounds__(256, 2) void k_om(
    const ushort* __restrict__ xt, const float* __restrict__ U,
    const ushort* __restrict__ womt, const float* __restrict__ womu,
    const float* __restrict__ bom, float* __restrict__ omt)
{
    int b, h; bhmap(b, h);
    const int tid = threadIdx.x;
    const int wid = tid >> 6, lane = tid & 63, lq = lane & 15, quad = lane >> 4;
    const int pixbase = wid * 32;

    __shared__ __align__(16) ushort As[128 * 128];   // 32 KB
    __shared__ __align__(16) ushort Bs[32 * 128];    // 8 KB
    __shared__ float U3[3 * 130];
    __shared__ float wu[288];

    f32x4 acc[2][2];
#pragma unroll
    for (int i = 0; i < 2; i++)
#pragma unroll
        for (int j = 0; j < 2; j++)
#pragma unroll
            for (int r = 0; r < 4; r++) acc[i][j][r] = 0.f;

    for (int s = tid; s < 390; s += 256) {
        int r = s / 130, c = s % 130, gy = h - 1 + r, gx = c - 1;
        float v = 0.f;
        if ((unsigned)gy < 128u && (unsigned)gx < 128u) {
            v = U[(size_t)b * HW + gy * 128 + gx];
            v = fminf(fmaxf(v, 0.f), 1.f);
        }
        U3[s] = v;
    }
    for (int s = tid; s < 288; s += 256) wu[s] = womu[s];

    const int row = tid >> 1, half = tid & 1;
    for (int t9 = 0; t9 < 9; t9++) {
        int dy = t9 / 3 - 1, dx = t9 % 3 - 1;
        int gy = h + dy, gx = row + dx;
        if ((unsigned)gy < 128u && (unsigned)gx < 128u) {
            const uint4* src = (const uint4*)(xt + (((size_t)b * HW) + gy * 128 + gx) * 128 + half * 64);
#pragma unroll
            for (int c8 = 0; c8 < 8; c8++) *(uint4*)&As[swz(row, half * 8 + c8)] = src[c8];
        } else {
            uint4 zz = {0, 0, 0, 0};
#pragma unroll
            for (int c8 = 0; c8 < 8; c8++) *(uint4*)&As[swz(row, half * 8 + c8)] = zz;
        }
        if (row < 32) {
            const uint4* src = (const uint4*)(womt + t9 * 4096 + row * 128 + half * 64);
#pragma unroll
            for (int c8 = 0; c8 < 8; c8++) *(uint4*)&Bs[swz(row, half * 8 + c8)] = src[c8];
        }
        __syncthreads();
#pragma unroll
        for (int kk = 0; kk < 4; kk++) {
            int chunk = kk * 4 + quad;
            bf16x8 av[2], bv[2];
#pragma unroll
            for (int i = 0; i < 2; i++) av[i] = *(const bf16x8*)&As[swz(pixbase + i * 16 + lq, chunk)];
#pragma unroll
            for (int j = 0; j < 2; j++) bv[j] = *(const bf16x8*)&Bs[swz(j * 16 + lq, chunk)];
#pragma unroll
            for (int i = 0; i < 2; i++)
#pragma unroll
                for (int j = 0; j < 2; j++)
                    acc[i][j] = __builtin_amdgcn_mfma_f32_16x16x32_bf16(av[i], bv[j], acc[i][j], 0, 0, 0);
        }
        __syncthreads();
    }

    // epilogue: + bias + U-channel conv term; sigmoid for mask channels
#pragma unroll
    for (int j = 0; j < 2; j++) {
        int oc = j * 16 + lq;
        if (oc < 27) {
            float bias = bom[oc];
#pragma unroll
            for (int i = 0; i < 2; i++)
#pragma unroll
                for (int r = 0; r < 4; r++) {
                    int pix = pixbase + i * 16 + quad * 4 + r;
                    float v = acc[i][j][r] + bias;
#pragma unroll
                    for (int t = 0; t < 9; t++)
                        v += U3[(t / 3) * 130 + pix + (t % 3)] * wu[t * 32 + oc];
                    if (oc >= 18) v = 2.f / (1.f + __expf(-v));
                    omt[((size_t)b * HW + h * 128 + pix) * 32 + oc] = v;
                }
        }
    }
}

// ---------------------------------------------------------------------------
// k_dcn: modulated deformable conv as MFMA GEMM.
// Staging v2: per-pixel corner table (offsets + masked weights) built in LDS
// during the previous tap's MFMA phase (double-buffered); gathers are
// 16-lane-contiguous per corner row (4 x 256B segments per wave-load).
// ---------------------------------------------------------------------------
__global__ __launch_bounds__(256, 2) void k_dcn(
    const ushort* __restrict__ xt, const float* __restrict__ omt,
    const ushort* __restrict__ wdt, const float* __restrict__ bdcn,
    ushort* __restrict__ zt)
{
    int b, h; bhmap(b, h);
    const int tid = threadIdx.x;
    const int wid = tid >> 6, lane = tid & 63, lq = lane & 15, quad = lane >> 4;
    const int pixbase = (wid & 1) * 64, ocbase = (wid >> 1) * 64;

    __shared__ __align__(16) ushort As[128 * 128];   // 32 KB
    __shared__ __align__(16) ushort Bs[128 * 128];   // 32 KB
    __shared__ __align__(16) int tbl[2][128][8];     // 8 KB: o00..o11, w00..w11

    // staging mapping: lane = (pixel-slot, chunk)
    const int sc = lane & 15;        // channel chunk 0..15 (8 ch each)
    const int sp = lane >> 4;        // pixel slot 0..3

    f32x4 acc[4][4];
#pragma unroll
    for (int i = 0; i < 4; i++)
#pragma unroll
        for (int j = 0; j < 4; j++)
#pragma unroll
            for (int r = 0; r < 4; r++) acc[i][j][r] = 0.f;

    const float* omrow = omt + ((size_t)b * HW + h * 128) * 32;
    const ushort* xtb = xt + (size_t)b * HW * 128;

    auto build = [&](int k, int buf) {
        if (tid < 128) {
            int p = tid;
            float dyv = omrow[p * 32 + 2 * k];
            float dxv = omrow[p * 32 + 2 * k + 1];
            float m   = omrow[p * 32 + 18 + k];
            float fy = (float)(h + k / 3 - 1) + dyv;
            float fx = (float)(p + k % 3 - 1) + dxv;
            float y0f = floorf(fy), x0f = floorf(fx);
            float ly = fy - y0f, lx = fx - x0f;
            float hy = 1.f - ly, hx = 1.f - lx;
            bool vy0 = (y0f >= 0.f) && (y0f <= 127.f);
            bool vy1 = (y0f >= -1.f) && (y0f <= 126.f);
            bool vx0 = (x0f >= 0.f) && (x0f <= 127.f);
            bool vx1 = (x0f >= -1.f) && (x0f <= 126.f);
            float w00 = (vy0 && vx0) ? hy * hx * m : 0.f;
            float w01 = (vy0 && vx1) ? hy * lx * m : 0.f;
            float w10 = (vy1 && vx0) ? ly * hx * m : 0.f;
            float w11 = (vy1 && vx1) ? ly * lx * m : 0.f;
            int iy0 = min(max((int)y0f, 0), 127);
            int iy1 = min(max((int)y0f + 1, 0), 127);
            int ix0 = min(max((int)x0f, 0), 127);
            int ix1 = min(max((int)x0f + 1, 0), 127);
            int* tp = &tbl[buf][p][0];
            tp[0] = (iy0 * 128 + ix0) * 128;
            tp[1] = (iy0 * 128 + ix1) * 128;
            tp[2] = (iy1 * 128 + ix0) * 128;
            tp[3] = (iy1 * 128 + ix1) * 128;
            ((float*)tp)[4] = w00; ((float*)tp)[5] = w01;
            ((float*)tp)[6] = w10; ((float*)tp)[7] = w11;
        }
    };

    build(0, 0);
    __syncthreads();

    const int brow = tid >> 1, bhalf = tid & 1;
    for (int k = 0; k < 9; k++) {
        const int buf = k & 1;
        // B: weights for tap k (coalesced)
        {
            const uint4* src = (const uint4*)(wdt + (size_t)k * 16384 + brow * 128 + bhalf * 64);
#pragma unroll
            for (int c8 = 0; c8 < 8; c8++) *(uint4*)&Bs[swz(brow, bhalf * 8 + c8)] = src[c8];
        }
        // A: 8 rounds, 4 pixels per wave per round, 16 lanes span one corner row
        const ushort* basep = xtb + sc * 8;
#pragma unroll 2
        for (int r = 0; r < 8; r++) {
            int p = wid * 32 + r * 4 + sp;
            int4 off = *(const int4*)&tbl[buf][p][0];
            f32x4 wv = *(const f32x4*)((const float*)&tbl[buf][p][0] + 4);
            uint4 q00 = *(const uint4*)(basep + off.x);
            uint4 q01 = *(const uint4*)(basep + off.y);
            uint4 q10 = *(const uint4*)(basep + off.z);
            uint4 q11 = *(const uint4*)(basep + off.w);
            uint4 st;
            st.x = blend2(q00.x, q01.x, q10.x, q11.x, wv[0], wv[1], wv[2], wv[3]);
            st.y = blend2(q00.y, q01.y, q10.y, q11.y, wv[0], wv[1], wv[2], wv[3]);
            st.z = blend2(q00.z, q01.z, q10.z, q11.z, wv[0], wv[1], wv[2], wv[3]);
            st.w = blend2(q00.w, q01.w, q10.w, q11.w, wv[0], wv[1], wv[2], wv[3]);
            *(uint4*)&As[swz(p, sc)] = st;
        }
        __syncthreads();
        // next tap's corner table hides behind MFMA
        if (k < 8) build(k + 1, buf ^ 1);
#pragma unroll
        for (int kk = 0; kk < 4; kk++) {
            int chunk = kk * 4 + quad;
            bf16x8 av[4], bv[4];
#pragma unroll
            for (int i = 0; i < 4; i++) av[i] = *(const bf16x8*)&As[swz(pixbase + i * 16 + lq, chunk)];
#pragma unroll
            for (int j = 0; j < 4; j++) bv[j] = *(const bf16x8*)&Bs[swz(ocbase + j * 16 + lq, chunk)];
#pragma unroll
            for (int i = 0; i < 4; i++)
#pragma unroll
                for (int j = 0; j < 4; j++)
                    acc[i][j] = __builtin_amdgcn_mfma_f32_16x16x32_bf16(av[i], bv[j], acc[i][j], 0, 0, 0);
        }
        __syncthreads();
    }

    size_t prow = ((size_t)b * HW + h * 128) * 128;
#pragma unroll
    for (int j = 0; j < 4; j++) {
        int oc = ocbase + j * 16 + lq;
        float bias = bdcn[oc];
#pragma unroll
        for (int i = 0; i < 4; i++)
#pragma unroll
            for (int r = 0; r < 4; r++) {
                int pix = pixbase + i * 16 + quad * 4 + r;
                zt[prow + (size_t)pix * 128 + oc] = f2bf(acc[i][j][r] + bias);
            }
    }
}

// ---------------------------------------------------------------------------
// k_conv1: r1 = relu(conv3x3(z) + b1), NHWC bf16 in/out. M=pix, N=oc.
// ---------------------------------------------------------------------------
__global__ __launch_bounds__(256, 2) void k_conv1(
    const ushort* __restrict__ zt, const ushort* __restrict__ w1t,
    const float* __restrict__ b1, ushort* __restrict__ r1t)
{
    int b, h; bhmap(b, h);
    const int tid = threadIdx.x;
    const int wid = tid >> 6, lane = tid & 63, lq = lane & 15, quad = lane >> 4;
    const int pixbase = (wid & 1) * 64, ocbase = (wid >> 1) * 64;

    __shared__ __align__(16) ushort As[128 * 128];
    __shared__ __align__(16) ushort Bs[128 * 128];

    f32x4 acc[4][4];
#pragma unroll
    for (int i = 0; i < 4; i++)
#pragma unroll
        for (int j = 0; j < 4; j++)
#pragma unroll
            for (int r = 0; r < 4; r++) acc[i][j][r] = 0.f;

    const int row = tid >> 1, half = tid & 1;
    for (int t9 = 0; t9 < 9; t9++) {
        int dy = t9 / 3 - 1, dx = t9 % 3 - 1;
        int gy = h + dy, gx = row + dx;
        if ((unsigned)gy < 128u && (unsigned)gx < 128u) {
            const uint4* src = (const uint4*)(zt + (((size_t)b * HW) + gy * 128 + gx) * 128 + half * 64);
#pragma unroll
            for (int c8 = 0; c8 < 8; c8++) *(uint4*)&As[swz(row, half * 8 + c8)] = src[c8];
        } else {
            uint4 zz = {0, 0, 0, 0};
#pragma unroll
            for (int c8 = 0; c8 < 8; c8++) *(uint4*)&As[swz(row, half * 8 + c8)] = zz;
        }
        {
            const uint4* src = (const uint4*)(w1t + (size_t)t9 * 16384 + row * 128 + half * 64);
#pragma unroll
            for (int c8 = 0; c8 < 8; c8++) *(uint4*)&Bs[swz(row, half * 8 + c8)] = src[c8];
        }
        __syncthreads();
#pragma unroll
        for (int kk = 0; kk < 4; kk++) {
            int chunk = kk * 4 + quad;
            bf16x8 av[4], bv[4];
#pragma unroll
            for (int i = 0; i < 4; i++) av[i] = *(const bf16x8*)&As[swz(pixbase + i * 16 + lq, chunk)];
#pragma unroll
            for (int j = 0; j < 4; j++) bv[j] = *(const bf16x8*)&Bs[swz(ocbase + j * 16 + lq, chunk)];
#pragma unroll
            for (int i = 0; i < 4; i++)
#pragma unroll
                for (int j = 0; j < 4; j++)
                    acc[i][j] = __builtin_amdgcn_mfma_f32_16x16x32_bf16(av[i], bv[j], acc[i][j], 0, 0, 0);
        }
        __syncthreads();
    }

    size_t prow = ((size_t)b * HW + h * 128) * 128;
#pragma unroll
    for (int j = 0; j < 4; j++) {
        int oc = ocbase + j * 16 + lq;
        float bias = b1[oc];
#pragma unroll
        for (int i = 0; i < 4; i++)
#pragma unroll
            for (int r = 0; r < 4; r++) {
                int pix = pixbase + i * 16 + quad * 4 + r;
                r1t[prow + (size_t)pix * 128 + oc] = f2bf(fmaxf(acc[i][j][r] + bias, 0.f));
            }
    }
}

// ---------------------------------------------------------------------------
// k_conv2: out = relu(x + (conv3x3(r1)+b2) * sigmoid(10*(clipU-0.5))).
// Swapped roles: M=oc (A=w2), N=pix (B=r1 rows) so NCHW fp32 stores coalesce.
// ---------------------------------------------------------------------------
__global__ __launch_bounds__(256, 2) void k_conv2(
    const ushort* __restrict__ r1t, const ushort* __restrict__ w2t,
    const float* __restrict__ b2, const float* __restrict__ x,
    const float* __restrict__ U, float* __restrict__ out)
{
    int b, h; bhmap(b, h);
    const int tid = threadIdx.x;
    const int wid = tid >> 6, lane = tid & 63, lq = lane & 15, quad = lane >> 4;
    const int mbase = (wid & 1) * 64;   // oc
    const int nbase = (wid >> 1) * 64;  // pix

    __shared__ __align__(16) ushort As[128 * 128];  // weights  [oc][ci]
    __shared__ __align__(16) ushort Bs[128 * 128];  // activ.   [pix][ci]

    f32x4 acc[4][4];
#pragma unroll
    for (int i = 0; i < 4; i++)
#pragma unroll
        for (int j = 0; j < 4; j++)
#pragma unroll
            for (int r = 0; r < 4; r++) acc[i][j][r] = 0.f;

    const int row = tid >> 1, half = tid & 1;
    for (int t9 = 0; t9 < 9; t9++) {
        int dy = t9 / 3 - 1, dx = t9 % 3 - 1;
        {
            const uint4* src = (const uint4*)(w2t + (size_t)t9 * 16384 + row * 128 + half * 64);
#pragma unroll
            for (int c8 = 0; c8 < 8; c8++) *(uint4*)&As[swz(row, half * 8 + c8)] = src[c8];
        }
        int gy = h + dy, gx = row + dx;
        if ((unsigned)gy < 128u && (unsigned)gx < 128u) {
            const uint4* src = (const uint4*)(r1t + (((size_t)b * HW) + gy * 128 + gx) * 128 + half * 64);
#pragma unroll
            for (int c8 = 0; c8 < 8; c8++) *(uint4*)&Bs[swz(row, half * 8 + c8)] = src[c8];
        } else {
            uint4 zz = {0, 0, 0, 0};
#pragma unroll
            for (int c8 = 0; c8 < 8; c8++) *(uint4*)&Bs[swz(row, half * 8 + c8)] = zz;
        }
        __syncthreads();
#pragma unroll
        for (int kk = 0; kk < 4; kk++) {
            int chunk = kk * 4 + quad;
            bf16x8 av[4], bv[4];
#pragma unroll
            for (int i = 0; i < 4; i++) av[i] = *(const bf16x8*)&As[swz(mbase + i * 16 + lq, chunk)];
#pragma unroll
            for (int j = 0; j < 4; j++) bv[j] = *(const bf16x8*)&Bs[swz(nbase + j * 16 + lq, chunk)];
#pragma unroll
            for (int i = 0; i < 4; i++)
#pragma unroll
                for (int j = 0; j < 4; j++)
                    acc[i][j] = __builtin_amdgcn_mfma_f32_16x16x32_bf16(av[i], bv[j], acc[i][j], 0, 0, 0);
        }
        __syncthreads();
    }

#pragma unroll
    for (int j = 0; j < 4; j++) {
        int pix = nbase + j * 16 + lq;
        float u = U[(size_t)b * HW + h * 128 + pix];
        u = fminf(fmaxf(u, 0.f), 1.f);
        float g = 1.f / (1.f + __expf(-10.f * (u - 0.5f)));
#pragma unroll
        for (int i = 0; i < 4; i++) {
            f32x4 b4 = *(const f32x4*)&b2[mbase + i * 16 + quad * 4];
#pragma unroll
            for (int r = 0; r < 4; r++) {
                int oc = mbase + i * 16 + quad * 4 + r;
                size_t idx = ((size_t)(b * 128 + oc)) * HW + h * 128 + pix;
                float v = acc[i][j][r] + b4[r];
                out[idx] = fmaxf(x[idx] + v * g, 0.f);
            }
        }
    }
}

// ---------------------------------------------------------------------------
extern "C" void kernel_launch(void* const* d_in, const int* in_sizes, int n_in,
                              void* d_out, int out_size, void* d_ws, size_t ws_size,
                              hipStream_t stream)
{
    const float* x     = (const float*)d_in[0];
    const float* U     = (const float*)d_in[1];
    const float* w_om  = (const float*)d_in[2];
    const float* b_om  = (const float*)d_in[3];
    const float* w_dcn = (const float*)d_in[4];
    const float* b_dcn = (const float*)d_in[5];
    const float* w1    = (const float*)d_in[6];
    const float* b1    = (const float*)d_in[7];
    const float* w2    = (const float*)d_in[8];
    const float* b2    = (const float*)d_in[9];
    float* out = (float*)d_out;

    char* p = (char*)d_ws;
    ushort* xt   = (ushort*)p; p += (size_t)4 * HW * 128 * 2;   // 16.78 MB
    ushort* zt   = (ushort*)p; p += (size_t)4 * HW * 128 * 2;
    ushort* r1t  = (ushort*)p; p += (size_t)4 * HW * 128 * 2;
    float*  omt  = (float*)p;  p += (size_t)4 * HW * 32 * 4;    // 8.39 MB
    ushort* wdt  = (ushort*)p; p += 147456 * 2;
    ushort* w1t  = (ushort*)p; p += 147456 * 2;
    ushort* w2t  = (ushort*)p; p += 147456 * 2;
    ushort* womt = (ushort*)p; p += 36864 * 2;
    float*  womu = (float*)p;  p += 288 * 4;

    prep_w<<<576, 256, 0, stream>>>(w_dcn, w1, w2, w_om, wdt, w1t, w2t, womt, womu);
    prep_xt<<<dim3(128, 4), 256, 0, stream>>>(x, xt);
    k_om<<<dim3(128, 4), 256, 0, stream>>>(xt, U, womt, womu, b_om, omt);
    k_dcn<<<dim3(128, 4), 256, 0, stream>>>(xt, omt, wdt, b_dcn, zt);
    k_conv1<<<dim3(128, 4), 256, 0, stream>>>(zt, w1t, b1, r1t);
    k_conv2<<<dim3(128, 4), 256, 0, stream>>>(r1t, w2t, b2, x, U, out);
}

// Round 6
// 233.475 us; speedup vs baseline: 9.5939x; 1.1822x over previous
//
#include <hip/hip_runtime.h>
#include <math.h>

typedef unsigned int uint;
typedef unsigned short ushort;
typedef __attribute__((ext_vector_type(8))) __bf16 bf16x8;
typedef __attribute__((ext_vector_type(4))) float f32x4;

#define HW 16384   // 128*128

// ---------- helpers ----------
__device__ __forceinline__ ushort f2bf(float f) {          // fp32 -> bf16 RNE
    uint u = __float_as_uint(f);
    u += 0x7fffu + ((u >> 16) & 1u);
    return (ushort)(u >> 16);
}
// XCD-affinity swizzle: 512 blocks; remap so XCD k owns 64 contiguous (b,h)
// rows -> per-XCD L2 working set < 4 MB; producers/consumers share mapping.
__device__ __forceinline__ void bhmap(int& b, int& h) {
    int lin = blockIdx.y * (int)gridDim.x + blockIdx.x;
    int n = (lin & 7) * 64 + (lin >> 3);
    h = n & 127;
    b = n >> 7;
}
// swizzled element index into a [rows][128] bf16 LDS tile.
__device__ __forceinline__ int swz(int row, int chunk) {
    return row * 128 + ((chunk ^ (row & 15)) << 3);
}
// bilinear blend of 4 packed bf16 pairs -> packed bf16 pair
__device__ __forceinline__ uint blend2(uint a, uint b, uint c, uint d,
                                       float w00, float w01, float w10, float w11) {
    float lo = w00 * __uint_as_float(a << 16) + w01 * __uint_as_float(b << 16)
             + w10 * __uint_as_float(c << 16) + w11 * __uint_as_float(d << 16);
    float hi = w00 * __uint_as_float(a & 0xffff0000u) + w01 * __uint_as_float(b & 0xffff0000u)
             + w10 * __uint_as_float(c & 0xffff0000u) + w11 * __uint_as_float(d & 0xffff0000u);
    uint ul = __float_as_uint(lo); ul += 0x7fffu + ((ul >> 16) & 1u);
    uint uh = __float_as_uint(hi); uh += 0x7fffu + ((uh >> 16) & 1u);
    return (ul >> 16) | ((uh >> 16) << 16);
}

// ---------------------------------------------------------------------------
// Prep 1: weights -> bf16 [tap][oc][ci]; w_om -> [tap][32(pad)][128] + U-col table
// ---------------------------------------------------------------------------
__global__ __launch_bounds__(256) void prep_w(
    const float* __restrict__ wd, const float* __restrict__ w1,
    const float* __restrict__ w2, const float* __restrict__ wom,
    ushort* __restrict__ wdt, ushort* __restrict__ w1t,
    ushort* __restrict__ w2t, ushort* __restrict__ womt,
    float* __restrict__ womu)
{
    int i = blockIdx.x * 256 + threadIdx.x;
    if (i < 147456) {                       // [k][oc][ci], 9*128*128
        int k = i >> 14, oc = (i >> 7) & 127, ci = i & 127;
        int s = (oc * 128 + ci) * 9 + k;
        wdt[i] = f2bf(wd[s]);
        w1t[i] = f2bf(w1[s]);
        w2t[i] = f2bf(w2[s]);
    }
    if (i < 36864) {                        // [k][32][128]
        int k = i >> 12, oc = (i >> 7) & 31, ci = i & 127;
        womt[i] = (oc < 27) ? f2bf(wom[(oc * 129 + ci) * 9 + k]) : (ushort)0;
    }
    if (i < 288) {                          // U-channel column: [k][32]
        int k = i >> 5, oc = i & 31;
        womu[i] = (oc < 27) ? wom[(oc * 129 + 128) * 9 + k] : 0.f;
    }
}

// ---------------------------------------------------------------------------
// Prep 2: x NCHW fp32 -> x_t NHWC bf16, LDS-transposed per (b,h) row.
// ---------------------------------------------------------------------------
__global__ __launch_bounds__(256) void prep_xt(
    const float* __restrict__ x, ushort* __restrict__ xt)
{
    int b, h; bhmap(b, h);
    const int tid = threadIdx.x;
    __shared__ __align__(16) ushort T[128 * 136];   // [w][c], pad 8
    const int w0 = tid & 127, cg = tid >> 7;
#pragma unroll 4
    for (int it = 0; it < 64; it++) {
        int c = it * 2 + cg;
        float f = x[((size_t)(b * 128 + c)) * HW + h * 128 + w0];
        T[w0 * 136 + c] = f2bf(f);
    }
    __syncthreads();
    const int w1 = tid >> 1, half = tid & 1;
    uint4* dst = (uint4*)(xt + (((size_t)b * HW) + h * 128 + w1) * 128 + half * 64);
    const uint4* src = (const uint4*)&T[w1 * 136 + half * 64];
#pragma unroll
    for (int c8 = 0; c8 < 8; c8++) dst[c8] = src[c8];
}

// ---------------------------------------------------------------------------
// k_om: offset/mask head. 512 thr, 8 waves, wave tile 16 pix x 32 oc.
// ---------------------------------------------------------------------------
__global__ __launch_bounds__(512, 4) void k_om(
    const ushort* __restrict__ xt, const float* __restrict__ U,
    const ushort* __restrict__ womt, const float* __restrict__ womu,
    const float* __restrict__ bom, float* __restrict__ omt)
{
    int b, h; bhmap(b, h);
    const int tid = threadIdx.x;
    const int wid = tid >> 6, lane = tid & 63, lq = lane & 15, quad = lane >> 4;
    const int pixbase = wid * 16;

    __shared__ __align__(16) ushort As[128 * 128];   // 32 KB
    __shared__ __align__(16) ushort Bs[32 * 128];    // 8 KB
    __shared__ float U3[3 * 130];
    __shared__ float wu[288];

    f32x4 acc[2];
#pragma unroll
    for (int j = 0; j < 2; j++)
#pragma unroll
        for (int r = 0; r < 4; r++) acc[j][r] = 0.f;

    for (int s = tid; s < 390; s += 512) {
        int r = s / 130, c = s % 130, gy = h - 1 + r, gx = c - 1;
        float v = 0.f;
        if ((unsigned)gy < 128u && (unsigned)gx < 128u) {
            v = U[(size_t)b * HW + gy * 128 + gx];
            v = fminf(fmaxf(v, 0.f), 1.f);
        }
        U3[s] = v;
    }
    if (tid < 288) wu[tid] = womu[tid];

    const int arow = tid >> 2, aq = tid & 3;         // As: 4 x 16B per thread
    const int brow = tid >> 4, bchunk = tid & 15;    // Bs: 1 x 16B per thread
    for (int t9 = 0; t9 < 9; t9++) {
        int dy = t9 / 3 - 1, dx = t9 % 3 - 1;
        int gy = h + dy, gx = arow + dx;
        if ((unsigned)gy < 128u && (unsigned)gx < 128u) {
            const uint4* src = (const uint4*)(xt + (((size_t)b * HW) + gy * 128 + gx) * 128 + aq * 32);
#pragma unroll
            for (int c = 0; c < 4; c++) *(uint4*)&As[swz(arow, aq * 4 + c)] = src[c];
        } else {
            uint4 zz = {0, 0, 0, 0};
#pragma unroll
            for (int c = 0; c < 4; c++) *(uint4*)&As[swz(arow, aq * 4 + c)] = zz;
        }
        *(uint4*)&Bs[swz(brow, bchunk)] = *(const uint4*)(womt + t9 * 4096 + brow * 128 + bchunk * 8);
        __syncthreads();
#pragma unroll
        for (int kk = 0; kk < 4; kk++) {
            int chunk = kk * 4 + quad;
            bf16x8 av = *(const bf16x8*)&As[swz(pixbase + lq, chunk)];
            bf16x8 bv[2];
#pragma unroll
            for (int j = 0; j < 2; j++) bv[j] = *(const bf16x8*)&Bs[swz(j * 16 + lq, chunk)];
#pragma unroll
            for (int j = 0; j < 2; j++)
                acc[j] = __builtin_amdgcn_mfma_f32_16x16x32_bf16(av, bv[j], acc[j], 0, 0, 0);
        }
        __syncthreads();
    }

    // epilogue: + bias + U-channel conv term; sigmoid for mask channels
#pragma unroll
    for (int j = 0; j < 2; j++) {
        int oc = j * 16 + lq;
        if (oc < 27) {
            float bias = bom[oc];
#pragma unroll
            for (int r = 0; r < 4; r++) {
                int pix = pixbase + quad * 4 + r;
                float v = acc[j][r] + bias;
#pragma unroll
                for (int t = 0; t < 9; t++)
                    v += U3[(t / 3) * 130 + pix + (t % 3)] * wu[t * 32 + oc];
                if (oc >= 18) v = 2.f / (1.f + __expf(-v));
                omt[((size_t)b * HW + h * 128 + pix) * 32 + oc] = v;
            }
        }
    }
}

// ---------------------------------------------------------------------------
// k_dcn: modulated deformable conv as MFMA GEMM. 512 thr, 8 waves,
// wave tile 64 pix x 32 oc. Corner table double-buffered in LDS (built during
// previous tap's MFMA); gathers 16-lane-contiguous per corner row.
// ---------------------------------------------------------------------------
__global__ __launch_bounds__(512, 4) void k_dcn(
    const ushort* __restrict__ xt, const float* __restrict__ omt,
    const ushort* __restrict__ wdt, const float* __restrict__ bdcn,
    ushort* __restrict__ zt)
{
    int b, h; bhmap(b, h);
    const int tid = threadIdx.x;
    const int wid = tid >> 6, lane = tid & 63, lq = lane & 15, quad = lane >> 4;
    const int pixbase = (wid & 1) * 64, ocbase = (wid >> 1) * 32;

    __shared__ __align__(16) ushort As[128 * 128];   // 32 KB
    __shared__ __align__(16) ushort Bs[128 * 128];   // 32 KB
    __shared__ __align__(16) int tbl[2][128][8];     // 8 KB

    const int sc = lane & 15;        // channel chunk
    const int sp = lane >> 4;        // pixel slot

    f32x4 acc[4][2];
#pragma unroll
    for (int i = 0; i < 4; i++)
#pragma unroll
        for (int j = 0; j < 2; j++)
#pragma unroll
            for (int r = 0; r < 4; r++) acc[i][j][r] = 0.f;

    const float* omrow = omt + ((size_t)b * HW + h * 128) * 32;
    const ushort* xtb = xt + (size_t)b * HW * 128;

    auto build = [&](int k, int buf) {
        if (tid < 128) {
            int p = tid;
            float dyv = omrow[p * 32 + 2 * k];
            float dxv = omrow[p * 32 + 2 * k + 1];
            float m   = omrow[p * 32 + 18 + k];
            float fy = (float)(h + k / 3 - 1) + dyv;
            float fx = (float)(p + k % 3 - 1) + dxv;
            float y0f = floorf(fy), x0f = floorf(fx);
            float ly = fy - y0f, lx = fx - x0f;
            float hy = 1.f - ly, hx = 1.f - lx;
            bool vy0 = (y0f >= 0.f) && (y0f <= 127.f);
            bool vy1 = (y0f >= -1.f) && (y0f <= 126.f);
            bool vx0 = (x0f >= 0.f) && (x0f <= 127.f);
            bool vx1 = (x0f >= -1.f) && (x0f <= 126.f);
            float w00 = (vy0 && vx0) ? hy * hx * m : 0.f;
            float w01 = (vy0 && vx1) ? hy * lx * m : 0.f;
            float w10 = (vy1 && vx0) ? ly * hx * m : 0.f;
            float w11 = (vy1 && vx1) ? ly * lx * m : 0.f;
            int iy0 = min(max((int)y0f, 0), 127);
            int iy1 = min(max((int)y0f + 1, 0), 127);
            int ix0 = min(max((int)x0f, 0), 127);
            int ix1 = min(max((int)x0f + 1, 0), 127);
            int* tp = &tbl[buf][p][0];
            tp[0] = (iy0 * 128 + ix0) * 128;
            tp[1] = (iy0 * 128 + ix1) * 128;
            tp[2] = (iy1 * 128 + ix0) * 128;
            tp[3] = (iy1 * 128 + ix1) * 128;
            ((float*)tp)[4] = w00; ((float*)tp)[5] = w01;
            ((float*)tp)[6] = w10; ((float*)tp)[7] = w11;
        }
    };

    build(0, 0);
    __syncthreads();

    const int brow = tid >> 2, bq = tid & 3;   // Bs: 4 x 16B per thread
    for (int k = 0; k < 9; k++) {
        const int buf = k & 1;
        {
            const uint4* src = (const uint4*)(wdt + (size_t)k * 16384 + brow * 128 + bq * 32);
#pragma unroll
            for (int c = 0; c < 4; c++) *(uint4*)&Bs[swz(brow, bq * 4 + c)] = src[c];
        }
        // A: 4 rounds, 4 pixels per wave per round, 16 lanes span one corner row
        const ushort* basep = xtb + sc * 8;
#pragma unroll 2
        for (int r = 0; r < 4; r++) {
            int p = r * 32 + wid * 4 + sp;
            int4 off = *(const int4*)&tbl[buf][p][0];
            f32x4 wv = *(const f32x4*)((const float*)&tbl[buf][p][0] + 4);
            uint4 q00 = *(const uint4*)(basep + off.x);
            uint4 q01 = *(const uint4*)(basep + off.y);
            uint4 q10 = *(const uint4*)(basep + off.z);
            uint4 q11 = *(const uint4*)(basep + off.w);
            uint4 st;
            st.x = blend2(q00.x, q01.x, q10.x, q11.x, wv[0], wv[1], wv[2], wv[3]);
            st.y = blend2(q00.y, q01.y, q10.y, q11.y, wv[0], wv[1], wv[2], wv[3]);
            st.z = blend2(q00.z, q01.z, q10.z, q11.z, wv[0], wv[1], wv[2], wv[3]);
            st.w = blend2(q00.w, q01.w, q10.w, q11.w, wv[0], wv[1], wv[2], wv[3]);
            *(uint4*)&As[swz(p, sc)] = st;
        }
        __syncthreads();
        if (k < 8) build(k + 1, buf ^ 1);      // hides behind MFMA
#pragma unroll
        for (int kk = 0; kk < 4; kk++) {
            int chunk = kk * 4 + quad;
            bf16x8 av[4], bv[2];
#pragma unroll
            for (int i = 0; i < 4; i++) av[i] = *(const bf16x8*)&As[swz(pixbase + i * 16 + lq, chunk)];
#pragma unroll
            for (int j = 0; j < 2; j++) bv[j] = *(const bf16x8*)&Bs[swz(ocbase + j * 16 + lq, chunk)];
#pragma unroll
            for (int i = 0; i < 4; i++)
#pragma unroll
                for (int j = 0; j < 2; j++)
                    acc[i][j] = __builtin_amdgcn_mfma_f32_16x16x32_bf16(av[i], bv[j], acc[i][j], 0, 0, 0);
        }
        __syncthreads();
    }

    size_t prow = ((size_t)b * HW + h * 128) * 128;
#pragma unroll
    for (int j = 0; j < 2; j++) {
        int oc = ocbase + j * 16 + lq;
        float bias = bdcn[oc];
#pragma unroll
        for (int i = 0; i < 4; i++)
#pragma unroll
            for (int r = 0; r < 4; r++) {
                int pix = pixbase + i * 16 + quad * 4 + r;
                zt[prow + (size_t)pix * 128 + oc] = f2bf(acc[i][j][r] + bias);
            }
    }
}

// ---------------------------------------------------------------------------
// k_conv1: r1 = relu(conv3x3(z) + b1), NHWC bf16. 512 thr, wave tile 64x32.
// ---------------------------------------------------------------------------
__global__ __launch_bounds__(512, 4) void k_conv1(
    const ushort* __restrict__ zt, const ushort* __restrict__ w1t,
    const float* __restrict__ b1, ushort* __restrict__ r1t)
{
    int b, h; bhmap(b, h);
    const int tid = threadIdx.x;
    const int wid = tid >> 6, lane = tid & 63, lq = lane & 15, quad = lane >> 4;
    const int pixbase = (wid & 1) * 64, ocbase = (wid >> 1) * 32;

    __shared__ __align__(16) ushort As[128 * 128];
    __shared__ __align__(16) ushort Bs[128 * 128];

    f32x4 acc[4][2];
#pragma unroll
    for (int i = 0; i < 4; i++)
#pragma unroll
        for (int j = 0; j < 2; j++)
#pragma unroll
            for (int r = 0; r < 4; r++) acc[i][j][r] = 0.f;

    const int row = tid >> 2, q = tid & 3;
    for (int t9 = 0; t9 < 9; t9++) {
        int dy = t9 / 3 - 1, dx = t9 % 3 - 1;
        int gy = h + dy, gx = row + dx;
        if ((unsigned)gy < 128u && (unsigned)gx < 128u) {
            const uint4* src = (const uint4*)(zt + (((size_t)b * HW) + gy * 128 + gx) * 128 + q * 32);
#pragma unroll
            for (int c = 0; c < 4; c++) *(uint4*)&As[swz(row, q * 4 + c)] = src[c];
        } else {
            uint4 zz = {0, 0, 0, 0};
#pragma unroll
            for (int c = 0; c < 4; c++) *(uint4*)&As[swz(row, q * 4 + c)] = zz;
        }
        {
            const uint4* src = (const uint4*)(w1t + (size_t)t9 * 16384 + row * 128 + q * 32);
#pragma unroll
            for (int c = 0; c < 4; c++) *(uint4*)&Bs[swz(row, q * 4 + c)] = src[c];
        }
        __syncthreads();
#pragma unroll
        for (int kk = 0; kk < 4; kk++) {
            int chunk = kk * 4 + quad;
            bf16x8 av[4], bv[2];
#pragma unroll
            for (int i = 0; i < 4; i++) av[i] = *(const bf16x8*)&As[swz(pixbase + i * 16 + lq, chunk)];
#pragma unroll
            for (int j = 0; j < 2; j++) bv[j] = *(const bf16x8*)&Bs[swz(ocbase + j * 16 + lq, chunk)];
#pragma unroll
            for (int i = 0; i < 4; i++)
#pragma unroll
                for (int j = 0; j < 2; j++)
                    acc[i][j] = __builtin_amdgcn_mfma_f32_16x16x32_bf16(av[i], bv[j], acc[i][j], 0, 0, 0);
        }
        __syncthreads();
    }

    size_t prow = ((size_t)b * HW + h * 128) * 128;
#pragma unroll
    for (int j = 0; j < 2; j++) {
        int oc = ocbase + j * 16 + lq;
        float bias = b1[oc];
#pragma unroll
        for (int i = 0; i < 4; i++)
#pragma unroll
            for (int r = 0; r < 4; r++) {
                int pix = pixbase + i * 16 + quad * 4 + r;
                r1t[prow + (size_t)pix * 128 + oc] = f2bf(fmaxf(acc[i][j][r] + bias, 0.f));
            }
    }
}

// ---------------------------------------------------------------------------
// k_conv2: out = relu(x + (conv3x3(r1)+b2) * sigmoid(10*(clipU-0.5))).
// 512 thr; M=oc (A=w2), N=pix so NCHW fp32 stores coalesce. Wave tile 64x32.
// ---------------------------------------------------------------------------
__global__ __launch_bounds__(512, 4) void k_conv2(
    const ushort* __restrict__ r1t, const ushort* __restrict__ w2t,
    const float* __restrict__ b2, const float* __restrict__ x,
    const float* __restrict__ U, float* __restrict__ out)
{
    int b, h; bhmap(b, h);
    const int tid = threadIdx.x;
    const int wid = tid >> 6, lane = tid & 63, lq = lane & 15, quad = lane >> 4;
    const int mbase = (wid & 1) * 64;   // oc
    const int nbase = (wid >> 1) * 32;  // pix

    __shared__ __align__(16) ushort As[128 * 128];  // weights  [oc][ci]
    __shared__ __align__(16) ushort Bs[128 * 128];  // activ.   [pix][ci]

    f32x4 acc[4][2];
#pragma unroll
    for (int i = 0; i < 4; i++)
#pragma unroll
        for (int j = 0; j < 2; j++)
#pragma unroll
            for (int r = 0; r < 4; r++) acc[i][j][r] = 0.f;

    const int row = tid >> 2, q = tid & 3;
    for (int t9 = 0; t9 < 9; t9++) {
        int dy = t9 / 3 - 1, dx = t9 % 3 - 1;
        {
            const uint4* src = (const uint4*)(w2t + (size_t)t9 * 16384 + row * 128 + q * 32);
#pragma unroll
            for (int c = 0; c < 4; c++) *(uint4*)&As[swz(row, q * 4 + c)] = src[c];
        }
        int gy = h + dy, gx = row + dx;
        if ((unsigned)gy < 128u && (unsigned)gx < 128u) {
            const uint4* src = (const uint4*)(r1t + (((size_t)b * HW) + gy * 128 + gx) * 128 + q * 32);
#pragma unroll
            for (int c = 0; c < 4; c++) *(uint4*)&Bs[swz(row, q * 4 + c)] = src[c];
        } else {
            uint4 zz = {0, 0, 0, 0};
#pragma unroll
            for (int c = 0; c < 4; c++) *(uint4*)&Bs[swz(row, q * 4 + c)] = zz;
        }
        __syncthreads();
#pragma unroll
        for (int kk = 0; kk < 4; kk++) {
            int chunk = kk * 4 + quad;
            bf16x8 av[4], bv[2];
#pragma unroll
            for (int i = 0; i < 4; i++) av[i] = *(const bf16x8*)&As[swz(mbase + i * 16 + lq, chunk)];
#pragma unroll
            for (int j = 0; j < 2; j++) bv[j] = *(const bf16x8*)&Bs[swz(nbase + j * 16 + lq, chunk)];
#pragma unroll
            for (int i = 0; i < 4; i++)
#pragma unroll
                for (int j = 0; j < 2; j++)
                    acc[i][j] = __builtin_amdgcn_mfma_f32_16x16x32_bf16(av[i], bv[j], acc[i][j], 0, 0, 0);
        }
        __syncthreads();
    }

#pragma unroll
    for (int j = 0; j < 2; j++) {
        int pix = nbase + j * 16 + lq;
        float u = U[(size_t)b * HW + h * 128 + pix];
        u = fminf(fmaxf(u, 0.f), 1.f);
        float g = 1.f / (1.f + __expf(-10.f * (u - 0.5f)));
#pragma unroll
        for (int i = 0; i < 4; i++) {
            f32x4 b4 = *(const f32x4*)&b2[mbase + i * 16 + quad * 4];
#pragma unroll
            for (int r = 0; r < 4; r++) {
                int oc = mbase + i * 16 + quad * 4 + r;
                size_t idx = ((size_t)(b * 128 + oc)) * HW + h * 128 + pix;
                float v = acc[i][j][r] + b4[r];
                out[idx] = fmaxf(x[idx] + v * g, 0.f);
            }
        }
    }
}

// ---------------------------------------------------------------------------
extern "C" void kernel_launch(void* const* d_in, const int* in_sizes, int n_in,
                              void* d_out, int out_size, void* d_ws, size_t ws_size,
                              hipStream_t stream)
{
    const float* x     = (const float*)d_in[0];
    const float* U     = (const float*)d_in[1];
    const float* w_om  = (const float*)d_in[2];
    const float* b_om  = (const float*)d_in[3];
    const float* w_dcn = (const float*)d_in[4];
    const float* b_dcn = (const float*)d_in[5];
    const float* w1    = (const float*)d_in[6];
    const float* b1    = (const float*)d_in[7];
    const float* w2    = (const float*)d_in[8];
    const float* b2    = (const float*)d_in[9];
    float* out = (float*)d_out;

    char* p = (char*)d_ws;
    ushort* xt   = (ushort*)p; p += (size_t)4 * HW * 128 * 2;   // 16.78 MB
    ushort* zt   = (ushort*)p; p += (size_t)4 * HW * 128 * 2;
    ushort* r1t  = (ushort*)p; p += (size_t)4 * HW * 128 * 2;
    float*  omt  = (float*)p;  p += (size_t)4 * HW * 32 * 4;    // 8.39 MB
    ushort* wdt  = (ushort*)p; p += 147456 * 2;
    ushort* w1t  = (ushort*)p; p += 147456 * 2;
    ushort* w2t  = (ushort*)p; p += 147456 * 2;
    ushort* womt = (ushort*)p; p += 36864 * 2;
    float*  womu = (float*)p;  p += 288 * 4;

    prep_w<<<576, 256, 0, stream>>>(w_dcn, w1, w2, w_om, wdt, w1t, w2t, womt, womu);
    prep_xt<<<dim3(128, 4), 256, 0, stream>>>(x, xt);
    k_om<<<dim3(128, 4), 512, 0, stream>>>(xt, U, womt, womu, b_om, omt);
    k_dcn<<<dim3(128, 4), 512, 0, stream>>>(xt, omt, wdt, b_dcn, zt);
    k_conv1<<<dim3(128, 4), 512, 0, stream>>>(zt, w1t, b1, r1t);
    k_conv2<<<dim3(128, 4), 512, 0, stream>>>(r1t, w2t, b2, x, U, out);
}